// Round 1
// baseline (566.887 us; speedup 1.0000x reference)
//
#include <hip/hip_runtime.h>
#include <hip/hip_bf16.h>

typedef unsigned short u16;
typedef unsigned int u32;
typedef unsigned long long u64;
typedef short bf16x8 __attribute__((ext_vector_type(8)));
typedef float f32x4 __attribute__((ext_vector_type(4)));
typedef u32 u32x4 __attribute__((ext_vector_type(4)));

#define T_DIM 2048
#define S_DIM 2048
#define H_DIM 128
#define KT 32
#define NKT (S_DIM / KT)
#define P_STR 40
#define SCL 0.12753257480082588f  // (1/sqrt(128)) * log2(e): softmax in exp2 domain
#define NEG_BIG -1e30f

// workspace layout (bytes)
#define KB_OFF 0u
#define KB_BYTES (64u * 2048u * 128u * 2u)            // 32 MB bf16 K
#define VT_OFF KB_BYTES
#define VT_BYTES (64u * 2048u * 128u * 2u)            // 32 MB bf16 V^T tiled
#define BM_OFF (KB_BYTES + VT_BYTES)
#define BM_BYTES (2u * 2048u * 2048u / 8u)            // 1 MB bitmask
#define WS_NEED ((size_t)(BM_OFF + BM_BYTES))

static __device__ __forceinline__ u16 f2b(float x) {
  return __builtin_bit_cast(u16, __float2bfloat16(x));
}
static __device__ __forceinline__ bf16x8 cvt8(float4 a, float4 b) {
  bf16x8 f;
  f[0] = (short)f2b(a.x); f[1] = (short)f2b(a.y);
  f[2] = (short)f2b(a.z); f[3] = (short)f2b(a.w);
  f[4] = (short)f2b(b.x); f[5] = (short)f2b(b.y);
  f[6] = (short)f2b(b.z); f[7] = (short)f2b(b.w);
  return f;
}

// packed RNE f32x2 -> bf16x2 (no builtin on gfx950; single VOP3)
static __device__ __forceinline__ u32 cvtpk_bf16(float lo, float hi) {
  u32 r;
  asm("v_cvt_pk_bf16_f32 %0, %1, %2" : "=v"(r) : "v"(lo), "v"(hi));
  return r;
}
// v_permlane32_swap_b32: newA=[A.r0,A.r1,B.r0,B.r1], newB=[A.r2,A.r3,B.r2,B.r3] (r = 16-lane row)
static __device__ __forceinline__ void pl32_swap(u32& a, u32& b) {
  asm("v_permlane32_swap_b32 %0, %1" : "+v"(a), "+v"(b));
}
// v_permlane16_swap_b32: newA=[A.r0,B.r0,A.r2,B.r2], newB=[A.r1,B.r1,A.r3,B.r3]
static __device__ __forceinline__ void pl16_swap(u32& a, u32& b) {
  asm("v_permlane16_swap_b32 %0, %1" : "+v"(a), "+v"(b));
}

template<int CTRL>
static __device__ __forceinline__ float dppf(float x) {
  return __builtin_bit_cast(float,
    __builtin_amdgcn_update_dpp(0, __builtin_bit_cast(int, x), CTRL, 0xf, 0xf, true));
}
static __device__ __forceinline__ float red16_sum(float x) {
  x += dppf<0xB1>(x);
  x += dppf<0x4E>(x);
  x += dppf<0x141>(x);
  x += dppf<0x140>(x);
  return x;
}

// async global->LDS, 16 B per lane; LDS dest = wave-uniform base + lane*16
static __device__ __forceinline__ void gl_lds16(const void* g, void* l) {
  __builtin_amdgcn_global_load_lds(
      (const __attribute__((address_space(1))) void*)g,
      (__attribute__((address_space(3))) void*)l, 16, 0, 0);
}

__global__ __launch_bounds__(256)
void cvt_k(const float* __restrict__ src, u16* __restrict__ dst) {
  size_t g = (size_t)(blockIdx.x * 256 + threadIdx.x) * 8;
  float4 a = *(const float4*)(src + g);
  float4 b = *(const float4*)(src + g + 4);
  *(bf16x8*)(dst + g) = cvt8(a, b);
}

// V [head][s][h] fp32 -> Vt [head][s/32][h][32 keys] bf16 (8 KB per tile)
__global__ __launch_bounds__(256)
void vt_pack(const float* __restrict__ V, u16* __restrict__ Vt) {
  __shared__ u16 Lt[32][136];
  const int hd = blockIdx.x >> 6;
  const int t  = blockIdx.x & 63;
  const int tid = threadIdx.x;
  const float* src = V + ((size_t)hd * S_DIM + (size_t)t * 32) * H_DIM;
  {
    int r = tid >> 3, h0 = (tid & 7) * 16;
    const float* sp = src + (size_t)r * H_DIM + h0;
    float4 a0 = *(const float4*)sp,      a1 = *(const float4*)(sp + 4);
    float4 a2 = *(const float4*)(sp + 8), a3 = *(const float4*)(sp + 12);
    *(bf16x8*)&Lt[r][h0]     = cvt8(a0, a1);
    *(bf16x8*)&Lt[r][h0 + 8] = cvt8(a2, a3);
  }
  __syncthreads();
  {
    int h = tid >> 1, k0 = (tid & 1) * 16;
    bf16x8 o0, o1;
#pragma unroll
    for (int j = 0; j < 8; ++j) o0[j] = (short)Lt[k0 + j][h];
#pragma unroll
    for (int j = 0; j < 8; ++j) o1[j] = (short)Lt[k0 + 8 + j][h];
    u16* dp = Vt + ((size_t)hd * 64 + t) * 4096 + (size_t)tid * 16;
    *(bf16x8*)dp = o0;
    *(bf16x8*)(dp + 8) = o1;
  }
}

__global__ __launch_bounds__(256)
void pack_mask(const int* __restrict__ M, u64* __restrict__ BM) {
  const int row  = blockIdx.x * 4 + (threadIdx.x >> 6);
  const int lane = threadIdx.x & 63;
  const int* mr = M + (size_t)row * S_DIM;
  u64* br = BM + (size_t)row * (S_DIM / 64);
  for (int s0 = 0; s0 < S_DIM; s0 += 64) {
    u64 b = __ballot(mr[s0 + lane] != 0);
    if (lane == 0) br[s0 >> 6] = b;
  }
}

// ---------------- main fused kernel ----------------
// Swapped-QK^T (mfma(K,Q) -> S^T, col=q) + in-register P transpose via
// cvt_pk_bf16 + permlane{32,16}_swap. No P LDS round-trip -> LDS = 32 KB
// -> 4 blocks/CU (whole 1024-block grid co-resident).
__global__ __launch_bounds__(256, 4)
void attn_fwd(const float* __restrict__ Q, const u16* __restrict__ Kb,
              const u16* __restrict__ Vtb, const u32* __restrict__ BM,
              float* __restrict__ O)
{
  // double-buffered, XOR-chunk-swizzled tiles (no padding: lds-DMA layout)
  __shared__ __align__(16) u16 KT2[2][32 * 128];   // K tile: [key][h], chunk^=(key&15)
  __shared__ __align__(16) u16 VT2[2][128 * 32];   // Vt tile: [h][key], chunk^=(h&3)

  const int tid  = threadIdx.x;
  const int wave = tid >> 6;
  const int lane = tid & 63;
  const int col  = lane & 15;
  const int quad = lane >> 4;

  // XCD-chunk swizzle (1024 wgs, 8 XCDs, 128/XCD): resident 32 blocks/XCD
  // cover 2 heads (2 MB K/V) -> fits the 4 MB per-XCD L2.
  const int wg = ((blockIdx.x & 7) << 7) | (blockIdx.x >> 3);
  const int head   = wg >> 4;
  const int qblock = wg & 15;
  const int batch  = head >> 5;
  const int q0w    = qblock * 128 + wave * 32;

  const float* Qh   = Q + (size_t)head * T_DIM * H_DIM;
  const char*  kb_t = (const char*)(Kb  + (size_t)head * S_DIM * H_DIM);
  const char*  vt_t = (const char*)(Vtb + (size_t)head * S_DIM * H_DIM);
  // per-lane mask rows: q = q0w + col (mi=0) and q0w + 16 + col (mi=1)
  const u32*   bmr0 = BM + ((size_t)batch * T_DIM + q0w + col) * (S_DIM / 32);
  const u32*   bmr1 = bmr0 + (size_t)16 * (S_DIM / 32);

  // per-lane global byte offsets for the 2 K-issues and 2 V-issues (constant)
  int koffb[2], voffb[2], lbase[2];
#pragma unroll
  for (int i = 0; i < 2; ++i) {
    int slot = wave * 64 + lane + 256 * i;
    int kr = slot >> 4, kc = slot & 15;
    koffb[i] = kr * 256 + ((kc ^ (kr & 15)) << 4);
    int vh = slot >> 2, vc = slot & 3;
    voffb[i] = vh * 64 + (((vc ^ vh) & 3) << 4);
    lbase[i] = (wave * 64 + 256 * i) * 8;   // u16 index of wave's slot group
  }

  // Q fragments, pre-scaled into exp2 domain. Used as MFMA *B* operand:
  // B[k=quad*8+j+32s][colq=lane&15], q-row = q0w + mi*16 + col.
  bf16x8 qf[2][4];
#pragma unroll
  for (int mi = 0; mi < 2; ++mi) {
    const float* qp = Qh + (size_t)(q0w + mi * 16 + col) * H_DIM + quad * 8;
#pragma unroll
    for (int s = 0; s < 4; ++s) {
      float4 a = *(const float4*)(qp + 32 * s);
      float4 b = *(const float4*)(qp + 32 * s + 4);
      a.x *= SCL; a.y *= SCL; a.z *= SCL; a.w *= SCL;
      b.x *= SCL; b.y *= SCL; b.z *= SCL; b.w *= SCL;
      qf[mi][s] = cvt8(a, b);
    }
  }

  f32x4 o[2][8];
#pragma unroll
  for (int mi = 0; mi < 2; ++mi)
#pragma unroll
    for (int c = 0; c < 8; ++c) o[mi][c] = (f32x4){0.f, 0.f, 0.f, 0.f};
  float l_p[2] = {0.f, 0.f};

  // stage tile 0
#pragma unroll
  for (int i = 0; i < 2; ++i) {
    gl_lds16(kb_t + koffb[i], (void*)&KT2[0][lbase[i]]);
    gl_lds16(vt_t + voffb[i], (void*)&VT2[0][lbase[i]]);
  }
  // mask words for tile 0 (pipelined one tile ahead)
  u32 wm0 = bmr0[0], wm1 = bmr1[0];

  for (int kt = 0; kt < NKT; ++kt) {
    // my tile-kt loads done; all waves past tile kt-1 compute
    asm volatile("s_waitcnt vmcnt(0) lgkmcnt(0)\n\ts_barrier" ::: "memory");

    if (kt + 1 < NKT) {
      const char* ks = kb_t + (size_t)(kt + 1) * 8192;
      const char* vs = vt_t + (size_t)(kt + 1) * 8192;
      const int nb = (kt + 1) & 1;
#pragma unroll
      for (int i = 0; i < 2; ++i) {
        gl_lds16(ks + koffb[i], (void*)&KT2[nb][lbase[i]]);
        gl_lds16(vs + voffb[i], (void*)&VT2[nb][lbase[i]]);
      }
    }

    const u16* Kc = &KT2[kt & 1][0];
    const u16* Vc = &VT2[kt & 1][0];

    u32 w0 = wm0, w1 = wm1;
    if (kt + 1 < NKT) { wm0 = bmr0[kt + 1]; wm1 = bmr1[kt + 1]; }

    // ---- swapped QK^T: S^T[key][q], D[row=key=4*quad+i (+16ki)][col=q] ----
    f32x4 s00 = {0,0,0,0}, s10 = {0,0,0,0}, s01 = {0,0,0,0}, s11 = {0,0,0,0};
#pragma unroll
    for (int s = 0; s < 4; ++s) {
      const int g = s * 4 + quad;
      bf16x8 kf0 = *(const bf16x8*)&Kc[col * 128 + ((g ^ col) & 15) * 8];
      bf16x8 kf1 = *(const bf16x8*)&Kc[(col + 16) * 128 + ((g ^ col) & 15) * 8];
      s00 = __builtin_amdgcn_mfma_f32_16x16x32_bf16(kf0, qf[0][s], s00, 0, 0, 0);
      s10 = __builtin_amdgcn_mfma_f32_16x16x32_bf16(kf1, qf[0][s], s10, 0, 0, 0);
      s01 = __builtin_amdgcn_mfma_f32_16x16x32_bf16(kf0, qf[1][s], s01, 0, 0, 0);
      s11 = __builtin_amdgcn_mfma_f32_16x16x32_bf16(kf1, qf[1][s], s11, 0, 0, 0);
    }

    // ---- softmax + in-register P transpose ----
    // lane holds P[key=16ki+4quad+i][q=16mi+col]; PV A-frag needs
    // P[q=16mi+col][key=8quad+j]: pack pairs, then quad redistribution via
    // permlane32_swap + permlane16_swap ({A,C}->{w0,w2}, {B,D}->{w1,w3}).
    bf16x8 pA[2];
#pragma unroll
    for (int mi = 0; mi < 2; ++mi) {
      f32x4 x0 = mi ? s01 : s00;   // keys 0..15 (local)
      f32x4 x1 = mi ? s11 : s10;   // keys 16..31
      u32 w = (mi ? w1 : w0) >> (quad * 4);
      float p0[4], p1[4];
#pragma unroll
      for (int i = 0; i < 4; ++i) {
        p0[i] = ((w >> i) & 1u)        ? exp2f(x0[i]) : 0.f;
        p1[i] = ((w >> (16 + i)) & 1u) ? exp2f(x1[i]) : 0.f;
      }
      l_p[mi] += ((p0[0] + p0[1]) + (p0[2] + p0[3])) +
                 ((p1[0] + p1[1]) + (p1[2] + p1[3]));
      u32 fa = cvtpk_bf16(p0[0], p0[1]);   // keys {4q, 4q+1}
      u32 fb = cvtpk_bf16(p0[2], p0[3]);   // keys {4q+2, 4q+3}
      u32 fc = cvtpk_bf16(p1[0], p1[1]);   // keys {16+4q, 17+4q}
      u32 fd = cvtpk_bf16(p1[2], p1[3]);   // keys {18+4q, 19+4q}
      pl32_swap(fa, fc); pl16_swap(fa, fc);  // fa=w0 {8q,8q+1}, fc=w2 {8q+4,8q+5}
      pl32_swap(fb, fd); pl16_swap(fb, fd);  // fb=w1 {8q+2,8q+3}, fd=w3 {8q+6,8q+7}
      u32x4 fr = {fa, fb, fc, fd};
      pA[mi] = __builtin_bit_cast(bf16x8, fr);
    }

    // ---- PV: O[32 x 128] += P[32 x 32] * V[32 x 128] ----
#pragma unroll
    for (int c = 0; c < 8; ++c) {
      bf16x8 vf = *(const bf16x8*)&Vc[(c * 16 + col) * 32 + ((quad ^ col) & 3) * 8];
      o[0][c] = __builtin_amdgcn_mfma_f32_16x16x32_bf16(pA[0], vf, o[0][c], 0, 0, 0);
      o[1][c] = __builtin_amdgcn_mfma_f32_16x16x32_bf16(pA[1], vf, o[1][c], 0, 0, 0);
    }
  }

  // ---- epilogue ----
  // l_p[mi] is the partial denominator for q = 16mi+col (keys {4quad..}+{16+4quad..}).
  // Cross-quad reduce in-register, then redistribute q->(4quad+i) rows through a
  // 128 B/wave scratch carved from the dead KT2[0] buffer (last tile used buf 1).
  float* sred = (float*)(&KT2[0][0]) + wave * 32;
#pragma unroll
  for (int mi = 0; mi < 2; ++mi) {
    u32 a = __builtin_bit_cast(u32, l_p[mi]), b = a;
    pl32_swap(a, b);           // a=[x0,x1,x0,x1], b=[x2,x3,x2,x3] (by quad)
    float s2 = __builtin_bit_cast(float, a) + __builtin_bit_cast(float, b);
    u32 c = __builtin_bit_cast(u32, s2), d = c;
    pl16_swap(c, d);           // c=[s0,s0,s2,s2], d=[s1,s1,s3,s3]
    float tot = __builtin_bit_cast(float, c) + __builtin_bit_cast(float, d);
    if (quad == 0) sred[mi * 16 + col] = tot;
  }
  asm volatile("s_waitcnt lgkmcnt(0)" ::: "memory");

  float* Oh = O + (size_t)head * T_DIM * H_DIM;
#pragma unroll
  for (int mi = 0; mi < 2; ++mi) {
    float4 lv = *(const float4*)&sred[mi * 16 + quad * 4];
    float invs[4] = {1.0f / lv.x, 1.0f / lv.y, 1.0f / lv.z, 1.0f / lv.w};
#pragma unroll
    for (int i = 0; i < 4; ++i) {
      float* orow = Oh + (size_t)(q0w + mi * 16 + quad * 4 + i) * H_DIM;
#pragma unroll
      for (int c = 0; c < 8; ++c)
        orow[c * 16 + col] = o[mi][c][i] * invs[i];
    }
  }
}

// ---------------- fallback (R3-verified, fp32 direct, no workspace) ----------------
__global__ __launch_bounds__(256, 2)
void attn_fb(const float* __restrict__ Q, const float* __restrict__ K,
             const float* __restrict__ V, const int* __restrict__ M,
             float* __restrict__ O)
{
  __shared__ __align__(16) u16 Kt[32 * 136];
  __shared__ __align__(16) u16 Vt[H_DIM * 40];
  __shared__ __align__(16) u16 Pt[4][32 * P_STR];

  const int tid  = threadIdx.x;
  const int wave = tid >> 6;
  const int lane = tid & 63;
  const int col  = lane & 15;
  const int quad = lane >> 4;
  const int head   = blockIdx.x >> 4;
  const int qblock = blockIdx.x & 15;
  const int batch  = head >> 5;
  const int q0w    = qblock * 128 + wave * 32;

  const float* Qh = Q + (size_t)head * T_DIM * H_DIM;
  const float* Kp = K + (size_t)head * S_DIM * H_DIM;
  const float* Vp = V + (size_t)head * S_DIM * H_DIM;
  const int*   Mb = M + (size_t)batch * T_DIM * S_DIM + (size_t)q0w * S_DIM;

  const int krow = tid >> 4;
  const int kc8  = (tid & 15) * 8;
  const float* kp0 = Kp + (size_t)krow * H_DIM + kc8;
  const float* kp1 = kp0 + (size_t)16 * H_DIM;
  const int vrow = tid & 31;
  const int vc8  = (tid >> 5) * 8;
  const float* vp0 = Vp + (size_t)vrow * H_DIM + vc8;
  const float* vp1 = vp0 + 64;

  bf16x8 qf[2][4];
#pragma unroll
  for (int mi = 0; mi < 2; ++mi) {
    const float* qp = Qh + (size_t)(q0w + mi * 16 + col) * H_DIM + quad * 8;
#pragma unroll
    for (int s = 0; s < 4; ++s) {
      float4 a = *(const float4*)(qp + 32 * s);
      float4 b = *(const float4*)(qp + 32 * s + 4);
      a.x *= SCL; a.y *= SCL; a.z *= SCL; a.w *= SCL;
      b.x *= SCL; b.y *= SCL; b.z *= SCL; b.w *= SCL;
      qf[mi][s] = cvt8(a, b);
    }
  }

  f32x4 o[2][8];
#pragma unroll
  for (int mi = 0; mi < 2; ++mi)
#pragma unroll
    for (int c = 0; c < 8; ++c) o[mi][c] = (f32x4){0.f,0.f,0.f,0.f};
  float l_p[2][4] = {{0.f,0.f,0.f,0.f},{0.f,0.f,0.f,0.f}};

  float4 ka00 = *(const float4*)kp0, ka01 = *(const float4*)(kp0 + 4);
  float4 ka10 = *(const float4*)kp1, ka11 = *(const float4*)(kp1 + 4);
  float4 va00 = *(const float4*)vp0, va01 = *(const float4*)(vp0 + 4);
  float4 va10 = *(const float4*)vp1, va11 = *(const float4*)(vp1 + 4);

  u16* Pw = &Pt[wave][0];

  for (int kt = 0; kt < NKT; ++kt) {
    asm volatile("s_waitcnt lgkmcnt(0)\n\ts_barrier" ::: "memory");
    *(bf16x8*)&Kt[krow * 136 + kc8]        = cvt8(ka00, ka01);
    *(bf16x8*)&Kt[(krow + 16) * 136 + kc8] = cvt8(ka10, ka11);
    {
      u16* v0 = &Vt[vc8 * 40 + vrow];
      v0[0*40] = f2b(va00.x); v0[1*40] = f2b(va00.y);
      v0[2*40] = f2b(va00.z); v0[3*40] = f2b(va00.w);
      v0[4*40] = f2b(va01.x); v0[5*40] = f2b(va01.y);
      v0[6*40] = f2b(va01.z); v0[7*40] = f2b(va01.w);
      u16* v1 = &Vt[(vc8 + 64) * 40 + vrow];
      v1[0*40] = f2b(va10.x); v1[1*40] = f2b(va10.y);
      v1[2*40] = f2b(va10.z); v1[3*40] = f2b(va10.w);
      v1[4*40] = f2b(va11.x); v1[5*40] = f2b(va11.y);
      v1[6*40] = f2b(va11.z); v1[7*40] = f2b(va11.w);
    }
    if (kt + 1 < NKT) {
      kp0 += KT * H_DIM; kp1 += KT * H_DIM; vp0 += KT * H_DIM; vp1 += KT * H_DIM;
      ka00 = *(const float4*)kp0; ka01 = *(const float4*)(kp0 + 4);
      ka10 = *(const float4*)kp1; ka11 = *(const float4*)(kp1 + 4);
      va00 = *(const float4*)vp0; va01 = *(const float4*)(vp0 + 4);
      va10 = *(const float4*)vp1; va11 = *(const float4*)(vp1 + 4);
    }
    asm volatile("s_waitcnt lgkmcnt(0)\n\ts_barrier" ::: "memory");

    f32x4 sc00 = {0,0,0,0}, sc01 = {0,0,0,0}, sc10 = {0,0,0,0}, sc11 = {0,0,0,0};
#pragma unroll
    for (int s = 0; s < 4; ++s) {
      bf16x8 kf0 = *(const bf16x8*)&Kt[col * 136 + s * 32 + quad * 8];
      bf16x8 kf1 = *(const bf16x8*)&Kt[(col + 16) * 136 + s * 32 + quad * 8];
      sc00 = __builtin_amdgcn_mfma_f32_16x16x32_bf16(qf[0][s], kf0, sc00, 0, 0, 0);
      sc01 = __builtin_amdgcn_mfma_f32_16x16x32_bf16(qf[0][s], kf1, sc01, 0, 0, 0);
      sc10 = __builtin_amdgcn_mfma_f32_16x16x32_bf16(qf[1][s], kf0, sc10, 0, 0, 0);
      sc11 = __builtin_amdgcn_mfma_f32_16x16x32_bf16(qf[1][s], kf1, sc11, 0, 0, 0);
    }

#pragma unroll
    for (int mi = 0; mi < 2; ++mi) {
      f32x4 s0 = mi ? sc10 : sc00;
      f32x4 s1 = mi ? sc11 : sc01;
#pragma unroll
      for (int i = 0; i < 4; ++i) {
        const int r = mi * 16 + quad * 4 + i;
        const int* mrow = Mb + (size_t)r * S_DIM + kt * KT;
        float p0 = mrow[col]      ? exp2f(s0[i]) : 0.f;
        float p1 = mrow[col + 16] ? exp2f(s1[i]) : 0.f;
        l_p[mi][i] += p0 + p1;
        Pw[r * P_STR + col]      = f2b(p0);
        Pw[r * P_STR + col + 16] = f2b(p1);
      }
    }

    bf16x8 pf0 = *(const bf16x8*)&Pw[col * P_STR + quad * 8];
    bf16x8 pf1 = *(const bf16x8*)&Pw[(col + 16) * P_STR + quad * 8];
#pragma unroll
    for (int c = 0; c < 8; ++c) {
      bf16x8 vf = *(const bf16x8*)&Vt[(c * 16 + col) * 40 + quad * 8];
      o[0][c] = __builtin_amdgcn_mfma_f32_16x16x32_bf16(pf0, vf, o[0][c], 0, 0, 0);
      o[1][c] = __builtin_amdgcn_mfma_f32_16x16x32_bf16(pf1, vf, o[1][c], 0, 0, 0);
    }
  }

  float* Oh = O + (size_t)head * T_DIM * H_DIM;
#pragma unroll
  for (int mi = 0; mi < 2; ++mi)
#pragma unroll
    for (int i = 0; i < 4; ++i) {
      float inv = 1.0f / red16_sum(l_p[mi][i]);
      float* orow = Oh + (size_t)(q0w + mi * 16 + quad * 4 + i) * H_DIM;
#pragma unroll
      for (int c = 0; c < 8; ++c)
        orow[c * 16 + col] = o[mi][c][i] * inv;
    }
}

extern "C" void kernel_launch(void* const* d_in, const int* in_sizes, int n_in,
                              void* d_out, int out_size, void* d_ws, size_t ws_size,
                              hipStream_t stream) {
  const float* q = (const float*)d_in[0];
  const float* k = (const float*)d_in[1];
  const float* v = (const float*)d_in[2];
  const int*   m = (const int*)d_in[3];
  float* out = (float*)d_out;

  if (d_ws != nullptr && ws_size >= WS_NEED) {
    u16* kb  = (u16*)((char*)d_ws + KB_OFF);
    u16* vtb = (u16*)((char*)d_ws + VT_OFF);
    u64* bm  = (u64*)((char*)d_ws + BM_OFF);
    cvt_k<<<dim3(8192), dim3(256), 0, stream>>>(k, kb);
    vt_pack<<<dim3(4096), dim3(256), 0, stream>>>(v, vtb);
    pack_mask<<<dim3((2 * T_DIM) / 4), dim3(256), 0, stream>>>(m, bm);
    attn_fwd<<<dim3(1024), dim3(256), 0, stream>>>(q, kb, vtb, (const u32*)bm, out);
  } else {
    attn_fb<<<dim3(1024), dim3(256), 0, stream>>>(q, k, v, m, out);
  }
}

// Round 3
// 441.706 us; speedup vs baseline: 1.2834x; 1.2834x over previous
//
#include <hip/hip_runtime.h>
#include <hip/hip_bf16.h>

typedef unsigned short u16;
typedef unsigned int u32;
typedef unsigned long long u64;
typedef short bf16x8 __attribute__((ext_vector_type(8)));
typedef float f32x4 __attribute__((ext_vector_type(4)));
typedef u32 u32x4 __attribute__((ext_vector_type(4)));

#define T_DIM 2048
#define S_DIM 2048
#define H_DIM 128
#define KT 32
#define NKT (S_DIM / KT)
#define P_STR 40
#define SCL 0.12753257480082588f  // (1/sqrt(128)) * log2(e): softmax in exp2 domain
#define NEG_BIG -1e30f

// workspace layout (bytes)
#define KB_OFF 0u
#define KB_BYTES (64u * 2048u * 128u * 2u)            // 32 MB bf16 K
#define VT_OFF KB_BYTES
#define VT_BYTES (64u * 2048u * 128u * 2u)            // 32 MB bf16 V^T tiled
#define BM_OFF (KB_BYTES + VT_BYTES)
#define BM_BYTES (2u * 2048u * 2048u / 8u)            // 1 MB bitmask
#define WS_NEED ((size_t)(BM_OFF + BM_BYTES))

static __device__ __forceinline__ u16 f2b(float x) {
  return __builtin_bit_cast(u16, __float2bfloat16(x));
}
static __device__ __forceinline__ bf16x8 cvt8(float4 a, float4 b) {
  bf16x8 f;
  f[0] = (short)f2b(a.x); f[1] = (short)f2b(a.y);
  f[2] = (short)f2b(a.z); f[3] = (short)f2b(a.w);
  f[4] = (short)f2b(b.x); f[5] = (short)f2b(b.y);
  f[6] = (short)f2b(b.z); f[7] = (short)f2b(b.w);
  return f;
}

// packed RNE f32x2 -> bf16x2 (no builtin on gfx950; single VOP3)
static __device__ __forceinline__ u32 cvtpk_bf16(float lo, float hi) {
  u32 r;
  asm("v_cvt_pk_bf16_f32 %0, %1, %2" : "=v"(r) : "v"(lo), "v"(hi));
  return r;
}
// v_permlane32_swap_b32: newA=[A.r0,A.r1,B.r0,B.r1], newB=[A.r2,A.r3,B.r2,B.r3] (r = 16-lane row)
static __device__ __forceinline__ void pl32_swap(u32& a, u32& b) {
  asm("v_permlane32_swap_b32 %0, %1" : "+v"(a), "+v"(b));
}
// v_permlane16_swap_b32: newA=[A.r0,B.r0,A.r2,B.r2], newB=[A.r1,B.r1,A.r3,B.r3]
static __device__ __forceinline__ void pl16_swap(u32& a, u32& b) {
  asm("v_permlane16_swap_b32 %0, %1" : "+v"(a), "+v"(b));
}

template<int CTRL>
static __device__ __forceinline__ float dppf(float x) {
  return __builtin_bit_cast(float,
    __builtin_amdgcn_update_dpp(0, __builtin_bit_cast(int, x), CTRL, 0xf, 0xf, true));
}
static __device__ __forceinline__ float red16_sum(float x) {
  x += dppf<0xB1>(x);
  x += dppf<0x4E>(x);
  x += dppf<0x141>(x);
  x += dppf<0x140>(x);
  return x;
}

// async global->LDS, 16 B per lane; LDS dest = wave-uniform base + lane*16
static __device__ __forceinline__ void gl_lds16(const void* g, void* l) {
  __builtin_amdgcn_global_load_lds(
      (const __attribute__((address_space(1))) void*)g,
      (__attribute__((address_space(3))) void*)l, 16, 0, 0);
}

__global__ __launch_bounds__(256)
void cvt_k(const float* __restrict__ src, u16* __restrict__ dst) {
  size_t g = (size_t)(blockIdx.x * 256 + threadIdx.x) * 8;
  float4 a = *(const float4*)(src + g);
  float4 b = *(const float4*)(src + g + 4);
  *(bf16x8*)(dst + g) = cvt8(a, b);
}

// V [head][s][h] fp32 -> Vt [head][s/32][h][32 keys] bf16 (8 KB per tile)
__global__ __launch_bounds__(256)
void vt_pack(const float* __restrict__ V, u16* __restrict__ Vt) {
  __shared__ u16 Lt[32][136];
  const int hd = blockIdx.x >> 6;
  const int t  = blockIdx.x & 63;
  const int tid = threadIdx.x;
  const float* src = V + ((size_t)hd * S_DIM + (size_t)t * 32) * H_DIM;
  {
    int r = tid >> 3, h0 = (tid & 7) * 16;
    const float* sp = src + (size_t)r * H_DIM + h0;
    float4 a0 = *(const float4*)sp,      a1 = *(const float4*)(sp + 4);
    float4 a2 = *(const float4*)(sp + 8), a3 = *(const float4*)(sp + 12);
    *(bf16x8*)&Lt[r][h0]     = cvt8(a0, a1);
    *(bf16x8*)&Lt[r][h0 + 8] = cvt8(a2, a3);
  }
  __syncthreads();
  {
    int h = tid >> 1, k0 = (tid & 1) * 16;
    bf16x8 o0, o1;
#pragma unroll
    for (int j = 0; j < 8; ++j) o0[j] = (short)Lt[k0 + j][h];
#pragma unroll
    for (int j = 0; j < 8; ++j) o1[j] = (short)Lt[k0 + 8 + j][h];
    u16* dp = Vt + ((size_t)hd * 64 + t) * 4096 + (size_t)tid * 16;
    *(bf16x8*)dp = o0;
    *(bf16x8*)(dp + 8) = o1;
  }
}

__global__ __launch_bounds__(256)
void pack_mask(const int* __restrict__ M, u64* __restrict__ BM) {
  const int row  = blockIdx.x * 4 + (threadIdx.x >> 6);
  const int lane = threadIdx.x & 63;
  const int* mr = M + (size_t)row * S_DIM;
  u64* br = BM + (size_t)row * (S_DIM / 64);
  for (int s0 = 0; s0 < S_DIM; s0 += 64) {
    u64 b = __ballot(mr[s0 + lane] != 0);
    if (lane == 0) br[s0 >> 6] = b;
  }
}

// ---------------- main fused kernel ----------------
// Round-1's verified math (swapped QK^T, in-register P transpose via
// cvt_pk_bf16 + permlane swaps) combined with round-0's verified scheduling:
// natural block order (NO XCD swizzle) and 2 blocks/CU. Occupancy is pinned
// by sizing LDS to 56 KB (the 24 KB EPAD block doubles as epilogue scratch):
// round 1 showed that 4 blocks/CU + swizzle exploded L2-miss traffic
// (67 MB -> 610 MB/iter) and regressed 290 -> 366 us.
__global__ __launch_bounds__(256, 2)
void attn_fwd(const float* __restrict__ Q, const u16* __restrict__ Kb,
              const u16* __restrict__ Vtb, const u32* __restrict__ BM,
              float* __restrict__ O)
{
  // double-buffered, XOR-chunk-swizzled tiles (no padding: lds-DMA layout)
  __shared__ __align__(16) u16 KT2[2][32 * 128];   // K tile: [key][h], chunk^=(key&15)
  __shared__ __align__(16) u16 VT2[2][128 * 32];   // Vt tile: [h][key], chunk^=(h&3)
  __shared__ __align__(16) float EPAD[6144];       // 24 KB: occupancy pin + epilogue scratch

  const int tid  = threadIdx.x;
  const int wave = tid >> 6;
  const int lane = tid & 63;
  const int col  = lane & 15;
  const int quad = lane >> 4;

  const int head   = blockIdx.x >> 4;
  const int qblock = blockIdx.x & 15;
  const int batch  = head >> 5;
  const int q0w    = qblock * 128 + wave * 32;

  const float* Qh   = Q + (size_t)head * T_DIM * H_DIM;
  const char*  kb_t = (const char*)(Kb  + (size_t)head * S_DIM * H_DIM);
  const char*  vt_t = (const char*)(Vtb + (size_t)head * S_DIM * H_DIM);
  // per-lane mask rows: q = q0w + col (mi=0) and q0w + 16 + col (mi=1)
  const u32*   bmr0 = BM + ((size_t)batch * T_DIM + q0w + col) * (S_DIM / 32);
  const u32*   bmr1 = bmr0 + (size_t)16 * (S_DIM / 32);

  // per-lane global byte offsets for the 2 K-issues and 2 V-issues (constant)
  int koffb[2], voffb[2], lbase[2];
#pragma unroll
  for (int i = 0; i < 2; ++i) {
    int slot = wave * 64 + lane + 256 * i;
    int kr = slot >> 4, kc = slot & 15;
    koffb[i] = kr * 256 + ((kc ^ (kr & 15)) << 4);
    int vh = slot >> 2, vc = slot & 3;
    voffb[i] = vh * 64 + (((vc ^ vh) & 3) << 4);
    lbase[i] = (wave * 64 + 256 * i) * 8;   // u16 index of wave's slot group
  }

  // Q fragments, pre-scaled into exp2 domain. Used as MFMA *B* operand:
  // B[k=quad*8+j+32s][colq=lane&15], q-row = q0w + mi*16 + col.
  bf16x8 qf[2][4];
#pragma unroll
  for (int mi = 0; mi < 2; ++mi) {
    const float* qp = Qh + (size_t)(q0w + mi * 16 + col) * H_DIM + quad * 8;
#pragma unroll
    for (int s = 0; s < 4; ++s) {
      float4 a = *(const float4*)(qp + 32 * s);
      float4 b = *(const float4*)(qp + 32 * s + 4);
      a.x *= SCL; a.y *= SCL; a.z *= SCL; a.w *= SCL;
      b.x *= SCL; b.y *= SCL; b.z *= SCL; b.w *= SCL;
      qf[mi][s] = cvt8(a, b);
    }
  }

  f32x4 o[2][8];
#pragma unroll
  for (int mi = 0; mi < 2; ++mi)
#pragma unroll
    for (int c = 0; c < 8; ++c) o[mi][c] = (f32x4){0.f, 0.f, 0.f, 0.f};
  float l_p[2] = {0.f, 0.f};

  // stage tile 0
#pragma unroll
  for (int i = 0; i < 2; ++i) {
    gl_lds16(kb_t + koffb[i], (void*)&KT2[0][lbase[i]]);
    gl_lds16(vt_t + voffb[i], (void*)&VT2[0][lbase[i]]);
  }
  // mask words for tile 0 (pipelined one tile ahead)
  u32 wm0 = bmr0[0], wm1 = bmr1[0];

  for (int kt = 0; kt < NKT; ++kt) {
    // my tile-kt loads done; all waves past tile kt-1 compute
    asm volatile("s_waitcnt vmcnt(0) lgkmcnt(0)\n\ts_barrier" ::: "memory");

    if (kt + 1 < NKT) {
      const char* ks = kb_t + (size_t)(kt + 1) * 8192;
      const char* vs = vt_t + (size_t)(kt + 1) * 8192;
      const int nb = (kt + 1) & 1;
#pragma unroll
      for (int i = 0; i < 2; ++i) {
        gl_lds16(ks + koffb[i], (void*)&KT2[nb][lbase[i]]);
        gl_lds16(vs + voffb[i], (void*)&VT2[nb][lbase[i]]);
      }
    }

    const u16* Kc = &KT2[kt & 1][0];
    const u16* Vc = &VT2[kt & 1][0];

    u32 w0 = wm0, w1 = wm1;
    if (kt + 1 < NKT) { wm0 = bmr0[kt + 1]; wm1 = bmr1[kt + 1]; }

    // ---- swapped QK^T: S^T[key][q], D[row=key=4*quad+i (+16ki)][col=q] ----
    f32x4 s00 = {0,0,0,0}, s10 = {0,0,0,0}, s01 = {0,0,0,0}, s11 = {0,0,0,0};
#pragma unroll
    for (int s = 0; s < 4; ++s) {
      const int g = s * 4 + quad;
      bf16x8 kf0 = *(const bf16x8*)&Kc[col * 128 + ((g ^ col) & 15) * 8];
      bf16x8 kf1 = *(const bf16x8*)&Kc[(col + 16) * 128 + ((g ^ col) & 15) * 8];
      s00 = __builtin_amdgcn_mfma_f32_16x16x32_bf16(kf0, qf[0][s], s00, 0, 0, 0);
      s10 = __builtin_amdgcn_mfma_f32_16x16x32_bf16(kf1, qf[0][s], s10, 0, 0, 0);
      s01 = __builtin_amdgcn_mfma_f32_16x16x32_bf16(kf0, qf[1][s], s01, 0, 0, 0);
      s11 = __builtin_amdgcn_mfma_f32_16x16x32_bf16(kf1, qf[1][s], s11, 0, 0, 0);
    }

    // ---- softmax + in-register P transpose ----
    // lane holds P[key=16ki+4quad+i][q=16mi+col]; PV A-frag needs
    // P[q=16mi+col][key=8quad+j]: pack pairs, then quad redistribution via
    // permlane32_swap + permlane16_swap ({A,C}->{w0,w2}, {B,D}->{w1,w3}).
    bf16x8 pA[2];
#pragma unroll
    for (int mi = 0; mi < 2; ++mi) {
      f32x4 x0 = mi ? s01 : s00;   // keys 0..15 (local)
      f32x4 x1 = mi ? s11 : s10;   // keys 16..31
      u32 w = (mi ? w1 : w0) >> (quad * 4);
      float p0[4], p1[4];
#pragma unroll
      for (int i = 0; i < 4; ++i) {
        p0[i] = ((w >> i) & 1u)        ? exp2f(x0[i]) : 0.f;
        p1[i] = ((w >> (16 + i)) & 1u) ? exp2f(x1[i]) : 0.f;
      }
      l_p[mi] += ((p0[0] + p0[1]) + (p0[2] + p0[3])) +
                 ((p1[0] + p1[1]) + (p1[2] + p1[3]));
      u32 fa = cvtpk_bf16(p0[0], p0[1]);   // keys {4q, 4q+1}
      u32 fb = cvtpk_bf16(p0[2], p0[3]);   // keys {4q+2, 4q+3}
      u32 fc = cvtpk_bf16(p1[0], p1[1]);   // keys {16+4q, 17+4q}
      u32 fd = cvtpk_bf16(p1[2], p1[3]);   // keys {18+4q, 19+4q}
      pl32_swap(fa, fc); pl16_swap(fa, fc);  // fa=w0 {8q,8q+1}, fc=w2 {8q+4,8q+5}
      pl32_swap(fb, fd); pl16_swap(fb, fd);  // fb=w1 {8q+2,8q+3}, fd=w3 {8q+6,8q+7}
      u32x4 fr = {fa, fb, fc, fd};
      pA[mi] = __builtin_bit_cast(bf16x8, fr);
    }

    // ---- PV: O[32 x 128] += P[32 x 32] * V[32 x 128] ----
#pragma unroll
    for (int c = 0; c < 8; ++c) {
      bf16x8 vf = *(const bf16x8*)&Vc[(c * 16 + col) * 32 + ((quad ^ col) & 3) * 8];
      o[0][c] = __builtin_amdgcn_mfma_f32_16x16x32_bf16(pA[0], vf, o[0][c], 0, 0, 0);
      o[1][c] = __builtin_amdgcn_mfma_f32_16x16x32_bf16(pA[1], vf, o[1][c], 0, 0, 0);
    }
  }

  // ---- epilogue ----
  // l_p[mi] is the partial denominator for q = 16mi+col. Cross-quad reduce
  // in-register, redistribute q->(4quad+i) rows through 128 B/wave of EPAD.
  float* sred = &EPAD[wave * 32];
#pragma unroll
  for (int mi = 0; mi < 2; ++mi) {
    u32 a = __builtin_bit_cast(u32, l_p[mi]), b = a;
    pl32_swap(a, b);           // a=[x0,x1,x0,x1], b=[x2,x3,x2,x3] (by quad)
    float s2 = __builtin_bit_cast(float, a) + __builtin_bit_cast(float, b);
    u32 c = __builtin_bit_cast(u32, s2), d = c;
    pl16_swap(c, d);           // c=[s0,s0,s2,s2], d=[s1,s1,s3,s3]
    float tot = __builtin_bit_cast(float, c) + __builtin_bit_cast(float, d);
    if (quad == 0) sred[mi * 16 + col] = tot;
  }
  asm volatile("s_waitcnt lgkmcnt(0)" ::: "memory");

  float* Oh = O + (size_t)head * T_DIM * H_DIM;
#pragma unroll
  for (int mi = 0; mi < 2; ++mi) {
    float4 lv = *(const float4*)&sred[mi * 16 + quad * 4];
    float invs[4] = {1.0f / lv.x, 1.0f / lv.y, 1.0f / lv.z, 1.0f / lv.w};
#pragma unroll
    for (int i = 0; i < 4; ++i) {
      float* orow = Oh + (size_t)(q0w + mi * 16 + quad * 4 + i) * H_DIM;
#pragma unroll
      for (int c = 0; c < 8; ++c)
        orow[c * 16 + col] = o[mi][c][i] * invs[i];
    }
  }
}

// ---------------- fallback (R3-verified, fp32 direct, no workspace) ----------------
__global__ __launch_bounds__(256, 2)
void attn_fb(const float* __restrict__ Q, const float* __restrict__ K,
             const float* __restrict__ V, const int* __restrict__ M,
             float* __restrict__ O)
{
  __shared__ __align__(16) u16 Kt[32 * 136];
  __shared__ __align__(16) u16 Vt[H_DIM * 40];
  __shared__ __align__(16) u16 Pt[4][32 * P_STR];

  const int tid  = threadIdx.x;
  const int wave = tid >> 6;
  const int lane = tid & 63;
  const int col  = lane & 15;
  const int quad = lane >> 4;
  const int head   = blockIdx.x >> 4;
  const int qblock = blockIdx.x & 15;
  const int batch  = head >> 5;
  const int q0w    = qblock * 128 + wave * 32;

  const float* Qh = Q + (size_t)head * T_DIM * H_DIM;
  const float* Kp = K + (size_t)head * S_DIM * H_DIM;
  const float* Vp = V + (size_t)head * S_DIM * H_DIM;
  const int*   Mb = M + (size_t)batch * T_DIM * S_DIM + (size_t)q0w * S_DIM;

  const int krow = tid >> 4;
  const int kc8  = (tid & 15) * 8;
  const float* kp0 = Kp + (size_t)krow * H_DIM + kc8;
  const float* kp1 = kp0 + (size_t)16 * H_DIM;
  const int vrow = tid & 31;
  const int vc8  = (tid >> 5) * 8;
  const float* vp0 = Vp + (size_t)vrow * H_DIM + vc8;
  const float* vp1 = vp0 + 64;

  bf16x8 qf[2][4];
#pragma unroll
  for (int mi = 0; mi < 2; ++mi) {
    const float* qp = Qh + (size_t)(q0w + mi * 16 + col) * H_DIM + quad * 8;
#pragma unroll
    for (int s = 0; s < 4; ++s) {
      float4 a = *(const float4*)(qp + 32 * s);
      float4 b = *(const float4*)(qp + 32 * s + 4);
      a.x *= SCL; a.y *= SCL; a.z *= SCL; a.w *= SCL;
      b.x *= SCL; b.y *= SCL; b.z *= SCL; b.w *= SCL;
      qf[mi][s] = cvt8(a, b);
    }
  }

  f32x4 o[2][8];
#pragma unroll
  for (int mi = 0; mi < 2; ++mi)
#pragma unroll
    for (int c = 0; c < 8; ++c) o[mi][c] = (f32x4){0.f,0.f,0.f,0.f};
  float l_p[2][4] = {{0.f,0.f,0.f,0.f},{0.f,0.f,0.f,0.f}};

  float4 ka00 = *(const float4*)kp0, ka01 = *(const float4*)(kp0 + 4);
  float4 ka10 = *(const float4*)kp1, ka11 = *(const float4*)(kp1 + 4);
  float4 va00 = *(const float4*)vp0, va01 = *(const float4*)(vp0 + 4);
  float4 va10 = *(const float4*)vp1, va11 = *(const float4*)(vp1 + 4);

  u16* Pw = &Pt[wave][0];

  for (int kt = 0; kt < NKT; ++kt) {
    asm volatile("s_waitcnt lgkmcnt(0)\n\ts_barrier" ::: "memory");
    *(bf16x8*)&Kt[krow * 136 + kc8]        = cvt8(ka00, ka01);
    *(bf16x8*)&Kt[(krow + 16) * 136 + kc8] = cvt8(ka10, ka11);
    {
      u16* v0 = &Vt[vc8 * 40 + vrow];
      v0[0*40] = f2b(va00.x); v0[1*40] = f2b(va00.y);
      v0[2*40] = f2b(va00.z); v0[3*40] = f2b(va00.w);
      v0[4*40] = f2b(va01.x); v0[5*40] = f2b(va01.y);
      v0[6*40] = f2b(va01.z); v0[7*40] = f2b(va01.w);
      u16* v1 = &Vt[(vc8 + 64) * 40 + vrow];
      v1[0*40] = f2b(va10.x); v1[1*40] = f2b(va10.y);
      v1[2*40] = f2b(va10.z); v1[3*40] = f2b(va10.w);
      v1[4*40] = f2b(va11.x); v1[5*40] = f2b(va11.y);
      v1[6*40] = f2b(va11.z); v1[7*40] = f2b(va11.w);
    }
    if (kt + 1 < NKT) {
      kp0 += KT * H_DIM; kp1 += KT * H_DIM; vp0 += KT * H_DIM; vp1 += KT * H_DIM;
      ka00 = *(const float4*)kp0; ka01 = *(const float4*)(kp0 + 4);
      ka10 = *(const float4*)kp1; ka11 = *(const float4*)(kp1 + 4);
      va00 = *(const float4*)vp0; va01 = *(const float4*)(vp0 + 4);
      va10 = *(const float4*)vp1; va11 = *(const float4*)(vp1 + 4);
    }
    asm volatile("s_waitcnt lgkmcnt(0)\n\ts_barrier" ::: "memory");

    f32x4 sc00 = {0,0,0,0}, sc01 = {0,0,0,0}, sc10 = {0,0,0,0}, sc11 = {0,0,0,0};
#pragma unroll
    for (int s = 0; s < 4; ++s) {
      bf16x8 kf0 = *(const bf16x8*)&Kt[col * 136 + s * 32 + quad * 8];
      bf16x8 kf1 = *(const bf16x8*)&Kt[(col + 16) * 136 + s * 32 + quad * 8];
      sc00 = __builtin_amdgcn_mfma_f32_16x16x32_bf16(qf[0][s], kf0, sc00, 0, 0, 0);
      sc01 = __builtin_amdgcn_mfma_f32_16x16x32_bf16(qf[0][s], kf1, sc01, 0, 0, 0);
      sc10 = __builtin_amdgcn_mfma_f32_16x16x32_bf16(qf[1][s], kf0, sc10, 0, 0, 0);
      sc11 = __builtin_amdgcn_mfma_f32_16x16x32_bf16(qf[1][s], kf1, sc11, 0, 0, 0);
    }

#pragma unroll
    for (int mi = 0; mi < 2; ++mi) {
      f32x4 s0 = mi ? sc10 : sc00;
      f32x4 s1 = mi ? sc11 : sc01;
#pragma unroll
      for (int i = 0; i < 4; ++i) {
        const int r = mi * 16 + quad * 4 + i;
        const int* mrow = Mb + (size_t)r * S_DIM + kt * KT;
        float p0 = mrow[col]      ? exp2f(s0[i]) : 0.f;
        float p1 = mrow[col + 16] ? exp2f(s1[i]) : 0.f;
        l_p[mi][i] += p0 + p1;
        Pw[r * P_STR + col]      = f2b(p0);
        Pw[r * P_STR + col + 16] = f2b(p1);
      }
    }

    bf16x8 pf0 = *(const bf16x8*)&Pw[col * P_STR + quad * 8];
    bf16x8 pf1 = *(const bf16x8*)&Pw[(col + 16) * P_STR + quad * 8];
#pragma unroll
    for (int c = 0; c < 8; ++c) {
      bf16x8 vf = *(const bf16x8*)&Vt[(c * 16 + col) * 40 + quad * 8];
      o[0][c] = __builtin_amdgcn_mfma_f32_16x16x32_bf16(pf0, vf, o[0][c], 0, 0, 0);
      o[1][c] = __builtin_amdgcn_mfma_f32_16x16x32_bf16(pf1, vf, o[1][c], 0, 0, 0);
    }
  }

  float* Oh = O + (size_t)head * T_DIM * H_DIM;
#pragma unroll
  for (int mi = 0; mi < 2; ++mi)
#pragma unroll
    for (int i = 0; i < 4; ++i) {
      float inv = 1.0f / red16_sum(l_p[mi][i]);
      float* orow = Oh + (size_t)(q0w + mi * 16 + quad * 4 + i) * H_DIM;
#pragma unroll
      for (int c = 0; c < 8; ++c)
        orow[c * 16 + col] = o[mi][c][i] * inv;
    }
}

extern "C" void kernel_launch(void* const* d_in, const int* in_sizes, int n_in,
                              void* d_out, int out_size, void* d_ws, size_t ws_size,
                              hipStream_t stream) {
  const float* q = (const float*)d_in[0];
  const float* k = (const float*)d_in[1];
  const float* v = (const float*)d_in[2];
  const int*   m = (const int*)d_in[3];
  float* out = (float*)d_out;

  if (d_ws != nullptr && ws_size >= WS_NEED) {
    u16* kb  = (u16*)((char*)d_ws + KB_OFF);
    u16* vtb = (u16*)((char*)d_ws + VT_OFF);
    u64* bm  = (u64*)((char*)d_ws + BM_OFF);
    cvt_k<<<dim3(8192), dim3(256), 0, stream>>>(k, kb);
    vt_pack<<<dim3(4096), dim3(256), 0, stream>>>(v, vtb);
    pack_mask<<<dim3((2 * T_DIM) / 4), dim3(256), 0, stream>>>(m, bm);
    attn_fwd<<<dim3(1024), dim3(256), 0, stream>>>(q, kb, vtb, (const u32*)bm, out);
  } else {
    attn_fb<<<dim3(1024), dim3(256), 0, stream>>>(q, k, v, m, out);
  }
}

// Round 6
// 438.112 us; speedup vs baseline: 1.2939x; 1.0082x over previous
//
#include <hip/hip_runtime.h>
#include <hip/hip_bf16.h>

typedef unsigned short u16;
typedef unsigned int u32;
typedef unsigned long long u64;
typedef short bf16x8 __attribute__((ext_vector_type(8)));
typedef float f32x4 __attribute__((ext_vector_type(4)));
typedef u32 u32x4 __attribute__((ext_vector_type(4)));

#define T_DIM 2048
#define S_DIM 2048
#define H_DIM 128
#define KT 32
#define NKT (S_DIM / KT)
#define P_STR 40
#define SCL 0.12753257480082588f  // (1/sqrt(128)) * log2(e): softmax in exp2 domain
#define NEG_BIG -1e30f

// workspace layout (bytes)
#define KB_OFF 0u
#define KB_BYTES (64u * 2048u * 128u * 2u)            // 32 MB bf16 K
#define VT_OFF KB_BYTES
#define VT_BYTES (64u * 2048u * 128u * 2u)            // 32 MB bf16 V^T tiled
#define BM_OFF (KB_BYTES + VT_BYTES)
#define BM_BYTES (2u * 2048u * 2048u / 8u)            // 1 MB bitmask
#define WS_NEED ((size_t)(BM_OFF + BM_BYTES))

static __device__ __forceinline__ u16 f2b(float x) {
  return __builtin_bit_cast(u16, __float2bfloat16(x));
}
static __device__ __forceinline__ bf16x8 cvt8(float4 a, float4 b) {
  bf16x8 f;
  f[0] = (short)f2b(a.x); f[1] = (short)f2b(a.y);
  f[2] = (short)f2b(a.z); f[3] = (short)f2b(a.w);
  f[4] = (short)f2b(b.x); f[5] = (short)f2b(b.y);
  f[6] = (short)f2b(b.z); f[7] = (short)f2b(b.w);
  return f;
}

// packed RNE f32x2 -> bf16x2 (no builtin on gfx950; single VOP3)
static __device__ __forceinline__ u32 cvtpk_bf16(float lo, float hi) {
  u32 r;
  asm("v_cvt_pk_bf16_f32 %0, %1, %2" : "=v"(r) : "v"(lo), "v"(hi));
  return r;
}
// v_permlane32_swap_b32: newA=[A.r0,A.r1,B.r0,B.r1], newB=[A.r2,A.r3,B.r2,B.r3] (r = 16-lane row)
static __device__ __forceinline__ void pl32_swap(u32& a, u32& b) {
  asm("v_permlane32_swap_b32 %0, %1" : "+v"(a), "+v"(b));
}
// v_permlane16_swap_b32: newA=[A.r0,B.r0,A.r2,B.r2], newB=[A.r1,B.r1,A.r3,B.r3]
static __device__ __forceinline__ void pl16_swap(u32& a, u32& b) {
  asm("v_permlane16_swap_b32 %0, %1" : "+v"(a), "+v"(b));
}

template<int CTRL>
static __device__ __forceinline__ float dppf(float x) {
  return __builtin_bit_cast(float,
    __builtin_amdgcn_update_dpp(0, __builtin_bit_cast(int, x), CTRL, 0xf, 0xf, true));
}
static __device__ __forceinline__ float red16_sum(float x) {
  x += dppf<0xB1>(x);
  x += dppf<0x4E>(x);
  x += dppf<0x141>(x);
  x += dppf<0x140>(x);
  return x;
}

// async global->LDS, 16 B per lane; LDS dest = wave-uniform base + lane*16
static __device__ __forceinline__ void gl_lds16(const void* g, void* l) {
  __builtin_amdgcn_global_load_lds(
      (const __attribute__((address_space(1))) void*)g,
      (__attribute__((address_space(3))) void*)l, 16, 0, 0);
}

// ---------------- fused prep: cvt_k + vt_pack + pack_mask in one launch ----
// Bodies are verbatim from the verified separate kernels; only the block
// index is remapped. Saves 2 launch/graph-node gaps and makes the prep cost
// visible as a single dispatch in the profile.
#define CVT_BLOCKS  8192
#define VTP_BLOCKS  4096
#define MSK_BLOCKS  ((2 * T_DIM) / 4)
#define PREP_BLOCKS (CVT_BLOCKS + VTP_BLOCKS + MSK_BLOCKS)

__global__ __launch_bounds__(256)
void prep_fused(const float* __restrict__ Ksrc, u16* __restrict__ Kdst,
                const float* __restrict__ V, u16* __restrict__ Vt,
                const int* __restrict__ M, u64* __restrict__ BM) {
  __shared__ u16 Lt[32][136];
  const int bid = blockIdx.x;
  const int tid = threadIdx.x;

  if (bid < CVT_BLOCKS) {
    // ---- cvt_k ----
    size_t g = (size_t)(bid * 256 + tid) * 8;
    float4 a = *(const float4*)(Ksrc + g);
    float4 b = *(const float4*)(Ksrc + g + 4);
    *(bf16x8*)(Kdst + g) = cvt8(a, b);
  } else if (bid < CVT_BLOCKS + VTP_BLOCKS) {
    // ---- vt_pack: V [head][s][h] fp32 -> Vt [head][s/32][h][32 keys] bf16 ----
    const int b2 = bid - CVT_BLOCKS;
    const int hd = b2 >> 6;
    const int t  = b2 & 63;
    const float* src = V + ((size_t)hd * S_DIM + (size_t)t * 32) * H_DIM;
    {
      int r = tid >> 3, h0 = (tid & 7) * 16;
      const float* sp = src + (size_t)r * H_DIM + h0;
      float4 a0 = *(const float4*)sp,      a1 = *(const float4*)(sp + 4);
      float4 a2 = *(const float4*)(sp + 8), a3 = *(const float4*)(sp + 12);
      *(bf16x8*)&Lt[r][h0]     = cvt8(a0, a1);
      *(bf16x8*)&Lt[r][h0 + 8] = cvt8(a2, a3);
    }
    __syncthreads();
    {
      int h = tid >> 1, k0 = (tid & 1) * 16;
      bf16x8 o0, o1;
#pragma unroll
      for (int j = 0; j < 8; ++j) o0[j] = (short)Lt[k0 + j][h];
#pragma unroll
      for (int j = 0; j < 8; ++j) o1[j] = (short)Lt[k0 + 8 + j][h];
      u16* dp = Vt + ((size_t)hd * 64 + t) * 4096 + (size_t)tid * 16;
      *(bf16x8*)dp = o0;
      *(bf16x8*)(dp + 8) = o1;
    }
  } else {
    // ---- pack_mask ----
    const int b3 = bid - (CVT_BLOCKS + VTP_BLOCKS);
    const int row  = b3 * 4 + (tid >> 6);
    const int lane = tid & 63;
    const int* mr = M + (size_t)row * S_DIM;
    u64* br = BM + (size_t)row * (S_DIM / 64);
    for (int s0 = 0; s0 < S_DIM; s0 += 64) {
      u64 b = __ballot(mr[s0 + lane] != 0);
      if (lane == 0) br[s0 >> 6] = b;
    }
  }
}

// ---------------- main fused kernel ----------------
// Round-3 VERIFIED structure, byte-identical: swapped QK^T, in-register P
// transpose via cvt_pk_bf16 + permlane swaps, natural block order,
// 2 blocks/CU (LDS pinned at 57344 via EPAD), KT=32, NO setprio, OCML exp2f.
// Rounds 4/5 showed that adding s_setprio/fexp2 to this structure breaks
// correctness (suspected timing-exposed latent race) — do not re-add without
// isolating the mechanism.
__global__ __launch_bounds__(256, 2)
void attn_fwd(const float* __restrict__ Q, const u16* __restrict__ Kb,
              const u16* __restrict__ Vtb, const u32* __restrict__ BM,
              float* __restrict__ O)
{
  // double-buffered, XOR-chunk-swizzled tiles (no padding: lds-DMA layout)
  __shared__ __align__(16) u16 KT2[2][32 * 128];   // K tile: [key][h], chunk^=(key&15)
  __shared__ __align__(16) u16 VT2[2][128 * 32];   // Vt tile: [h][key], chunk^=(h&3)
  __shared__ __align__(16) float EPAD[6144];       // 24 KB: occupancy pin + epilogue scratch

  const int tid  = threadIdx.x;
  const int wave = tid >> 6;
  const int lane = tid & 63;
  const int col  = lane & 15;
  const int quad = lane >> 4;

  const int head   = blockIdx.x >> 4;
  const int qblock = blockIdx.x & 15;
  const int batch  = head >> 5;
  const int q0w    = qblock * 128 + wave * 32;

  const float* Qh   = Q + (size_t)head * T_DIM * H_DIM;
  const char*  kb_t = (const char*)(Kb  + (size_t)head * S_DIM * H_DIM);
  const char*  vt_t = (const char*)(Vtb + (size_t)head * S_DIM * H_DIM);
  // per-lane mask rows: q = q0w + col (mi=0) and q0w + 16 + col (mi=1)
  const u32*   bmr0 = BM + ((size_t)batch * T_DIM + q0w + col) * (S_DIM / 32);
  const u32*   bmr1 = bmr0 + (size_t)16 * (S_DIM / 32);

  // per-lane global byte offsets for the 2 K-issues and 2 V-issues (constant)
  int koffb[2], voffb[2], lbase[2];
#pragma unroll
  for (int i = 0; i < 2; ++i) {
    int slot = wave * 64 + lane + 256 * i;
    int kr = slot >> 4, kc = slot & 15;
    koffb[i] = kr * 256 + ((kc ^ (kr & 15)) << 4);
    int vh = slot >> 2, vc = slot & 3;
    voffb[i] = vh * 64 + (((vc ^ vh) & 3) << 4);
    lbase[i] = (wave * 64 + 256 * i) * 8;   // u16 index of wave's slot group
  }

  // Q fragments, pre-scaled into exp2 domain. Used as MFMA *B* operand:
  // B[k=quad*8+j+32s][colq=lane&15], q-row = q0w + mi*16 + col.
  bf16x8 qf[2][4];
#pragma unroll
  for (int mi = 0; mi < 2; ++mi) {
    const float* qp = Qh + (size_t)(q0w + mi * 16 + col) * H_DIM + quad * 8;
#pragma unroll
    for (int s = 0; s < 4; ++s) {
      float4 a = *(const float4*)(qp + 32 * s);
      float4 b = *(const float4*)(qp + 32 * s + 4);
      a.x *= SCL; a.y *= SCL; a.z *= SCL; a.w *= SCL;
      b.x *= SCL; b.y *= SCL; b.z *= SCL; b.w *= SCL;
      qf[mi][s] = cvt8(a, b);
    }
  }

  f32x4 o[2][8];
#pragma unroll
  for (int mi = 0; mi < 2; ++mi)
#pragma unroll
    for (int c = 0; c < 8; ++c) o[mi][c] = (f32x4){0.f, 0.f, 0.f, 0.f};
  float l_p[2] = {0.f, 0.f};

  // stage tile 0
#pragma unroll
  for (int i = 0; i < 2; ++i) {
    gl_lds16(kb_t + koffb[i], (void*)&KT2[0][lbase[i]]);
    gl_lds16(vt_t + voffb[i], (void*)&VT2[0][lbase[i]]);
  }
  // mask words for tile 0 (pipelined one tile ahead)
  u32 wm0 = bmr0[0], wm1 = bmr1[0];

  for (int kt = 0; kt < NKT; ++kt) {
    // my tile-kt loads done; all waves past tile kt-1 compute
    asm volatile("s_waitcnt vmcnt(0) lgkmcnt(0)\n\ts_barrier" ::: "memory");

    if (kt + 1 < NKT) {
      const char* ks = kb_t + (size_t)(kt + 1) * 8192;
      const char* vs = vt_t + (size_t)(kt + 1) * 8192;
      const int nb = (kt + 1) & 1;
#pragma unroll
      for (int i = 0; i < 2; ++i) {
        gl_lds16(ks + koffb[i], (void*)&KT2[nb][lbase[i]]);
        gl_lds16(vs + voffb[i], (void*)&VT2[nb][lbase[i]]);
      }
    }

    const u16* Kc = &KT2[kt & 1][0];
    const u16* Vc = &VT2[kt & 1][0];

    u32 w0 = wm0, w1 = wm1;
    if (kt + 1 < NKT) { wm0 = bmr0[kt + 1]; wm1 = bmr1[kt + 1]; }

    // ---- swapped QK^T: S^T[key][q], D[row=key=4*quad+i (+16ki)][col=q] ----
    f32x4 s00 = {0,0,0,0}, s10 = {0,0,0,0}, s01 = {0,0,0,0}, s11 = {0,0,0,0};
#pragma unroll
    for (int s = 0; s < 4; ++s) {
      const int g = s * 4 + quad;
      bf16x8 kf0 = *(const bf16x8*)&Kc[col * 128 + ((g ^ col) & 15) * 8];
      bf16x8 kf1 = *(const bf16x8*)&Kc[(col + 16) * 128 + ((g ^ col) & 15) * 8];
      s00 = __builtin_amdgcn_mfma_f32_16x16x32_bf16(kf0, qf[0][s], s00, 0, 0, 0);
      s10 = __builtin_amdgcn_mfma_f32_16x16x32_bf16(kf1, qf[0][s], s10, 0, 0, 0);
      s01 = __builtin_amdgcn_mfma_f32_16x16x32_bf16(kf0, qf[1][s], s01, 0, 0, 0);
      s11 = __builtin_amdgcn_mfma_f32_16x16x32_bf16(kf1, qf[1][s], s11, 0, 0, 0);
    }

    // ---- softmax + in-register P transpose ----
    // lane holds P[key=16ki+4quad+i][q=16mi+col]; PV A-frag needs
    // P[q=16mi+col][key=8quad+j]: pack pairs, then quad redistribution via
    // permlane32_swap + permlane16_swap ({A,C}->{w0,w2}, {B,D}->{w1,w3}).
    bf16x8 pA[2];
#pragma unroll
    for (int mi = 0; mi < 2; ++mi) {
      f32x4 x0 = mi ? s01 : s00;   // keys 0..15 (local)
      f32x4 x1 = mi ? s11 : s10;   // keys 16..31
      u32 w = (mi ? w1 : w0) >> (quad * 4);
      float p0[4], p1[4];
#pragma unroll
      for (int i = 0; i < 4; ++i) {
        p0[i] = ((w >> i) & 1u)        ? exp2f(x0[i]) : 0.f;
        p1[i] = ((w >> (16 + i)) & 1u) ? exp2f(x1[i]) : 0.f;
      }
      l_p[mi] += ((p0[0] + p0[1]) + (p0[2] + p0[3])) +
                 ((p1[0] + p1[1]) + (p1[2] + p1[3]));
      u32 fa = cvtpk_bf16(p0[0], p0[1]);   // keys {4q, 4q+1}
      u32 fb = cvtpk_bf16(p0[2], p0[3]);   // keys {4q+2, 4q+3}
      u32 fc = cvtpk_bf16(p1[0], p1[1]);   // keys {16+4q, 17+4q}
      u32 fd = cvtpk_bf16(p1[2], p1[3]);   // keys {18+4q, 19+4q}
      pl32_swap(fa, fc); pl16_swap(fa, fc);  // fa=w0 {8q,8q+1}, fc=w2 {8q+4,8q+5}
      pl32_swap(fb, fd); pl16_swap(fb, fd);  // fb=w1 {8q+2,8q+3}, fd=w3 {8q+6,8q+7}
      u32x4 fr = {fa, fb, fc, fd};
      pA[mi] = __builtin_bit_cast(bf16x8, fr);
    }

    // ---- PV: O[32 x 128] += P[32 x 32] * V[32 x 128] ----
#pragma unroll
    for (int c = 0; c < 8; ++c) {
      bf16x8 vf = *(const bf16x8*)&Vc[(c * 16 + col) * 32 + ((quad ^ col) & 3) * 8];
      o[0][c] = __builtin_amdgcn_mfma_f32_16x16x32_bf16(pA[0], vf, o[0][c], 0, 0, 0);
      o[1][c] = __builtin_amdgcn_mfma_f32_16x16x32_bf16(pA[1], vf, o[1][c], 0, 0, 0);
    }
  }

  // ---- epilogue ----
  // l_p[mi] is the partial denominator for q = 16mi+col. Cross-quad reduce
  // in-register, redistribute q->(4quad+i) rows through 128 B/wave of EPAD.
  float* sred = &EPAD[wave * 32];
#pragma unroll
  for (int mi = 0; mi < 2; ++mi) {
    u32 a = __builtin_bit_cast(u32, l_p[mi]), b = a;
    pl32_swap(a, b);           // a=[x0,x1,x0,x1], b=[x2,x3,x2,x3] (by quad)
    float s2 = __builtin_bit_cast(float, a) + __builtin_bit_cast(float, b);
    u32 c = __builtin_bit_cast(u32, s2), d = c;
    pl16_swap(c, d);           // c=[s0,s0,s2,s2], d=[s1,s1,s3,s3]
    float tot = __builtin_bit_cast(float, c) + __builtin_bit_cast(float, d);
    if (quad == 0) sred[mi * 16 + col] = tot;
  }
  asm volatile("s_waitcnt lgkmcnt(0)" ::: "memory");

  float* Oh = O + (size_t)head * T_DIM * H_DIM;
#pragma unroll
  for (int mi = 0; mi < 2; ++mi) {
    float4 lv = *(const float4*)&sred[mi * 16 + quad * 4];
    float invs[4] = {1.0f / lv.x, 1.0f / lv.y, 1.0f / lv.z, 1.0f / lv.w};
#pragma unroll
    for (int i = 0; i < 4; ++i) {
      float* orow = Oh + (size_t)(q0w + mi * 16 + quad * 4 + i) * H_DIM;
#pragma unroll
      for (int c = 0; c < 8; ++c)
        orow[c * 16 + col] = o[mi][c][i] * invs[i];
    }
  }
}

// ---------------- fallback (R3-verified, fp32 direct, no workspace) ----------------
__global__ __launch_bounds__(256, 2)
void attn_fb(const float* __restrict__ Q, const float* __restrict__ K,
             const float* __restrict__ V, const int* __restrict__ M,
             float* __restrict__ O)
{
  __shared__ __align__(16) u16 Kt[32 * 136];
  __shared__ __align__(16) u16 Vt[H_DIM * 40];
  __shared__ __align__(16) u16 Pt[4][32 * P_STR];

  const int tid  = threadIdx.x;
  const int wave = tid >> 6;
  const int lane = tid & 63;
  const int col  = lane & 15;
  const int quad = lane >> 4;
  const int head   = blockIdx.x >> 4;
  const int qblock = blockIdx.x & 15;
  const int batch  = head >> 5;
  const int q0w    = qblock * 128 + wave * 32;

  const float* Qh = Q + (size_t)head * T_DIM * H_DIM;
  const float* Kp = K + (size_t)head * S_DIM * H_DIM;
  const float* Vp = V + (size_t)head * S_DIM * H_DIM;
  const int*   Mb = M + (size_t)batch * T_DIM * S_DIM + (size_t)q0w * S_DIM;

  const int krow = tid >> 4;
  const int kc8  = (tid & 15) * 8;
  const float* kp0 = Kp + (size_t)krow * H_DIM + kc8;
  const float* kp1 = kp0 + (size_t)16 * H_DIM;
  const int vrow = tid & 31;
  const int vc8  = (tid >> 5) * 8;
  const float* vp0 = Vp + (size_t)vrow * H_DIM + vc8;
  const float* vp1 = vp0 + 64;

  bf16x8 qf[2][4];
#pragma unroll
  for (int mi = 0; mi < 2; ++mi) {
    const float* qp = Qh + (size_t)(q0w + mi * 16 + col) * H_DIM + quad * 8;
#pragma unroll
    for (int s = 0; s < 4; ++s) {
      float4 a = *(const float4*)(qp + 32 * s);
      float4 b = *(const float4*)(qp + 32 * s + 4);
      a.x *= SCL; a.y *= SCL; a.z *= SCL; a.w *= SCL;
      b.x *= SCL; b.y *= SCL; b.z *= SCL; b.w *= SCL;
      qf[mi][s] = cvt8(a, b);
    }
  }

  f32x4 o[2][8];
#pragma unroll
  for (int mi = 0; mi < 2; ++mi)
#pragma unroll
    for (int c = 0; c < 8; ++c) o[mi][c] = (f32x4){0.f,0.f,0.f,0.f};
  float l_p[2][4] = {{0.f,0.f,0.f,0.f},{0.f,0.f,0.f,0.f}};

  float4 ka00 = *(const float4*)kp0, ka01 = *(const float4*)(kp0 + 4);
  float4 ka10 = *(const float4*)kp1, ka11 = *(const float4*)(kp1 + 4);
  float4 va00 = *(const float4*)vp0, va01 = *(const float4*)(vp0 + 4);
  float4 va10 = *(const float4*)vp1, va11 = *(const float4*)(vp1 + 4);

  u16* Pw = &Pt[wave][0];

  for (int kt = 0; kt < NKT; ++kt) {
    asm volatile("s_waitcnt lgkmcnt(0)\n\ts_barrier" ::: "memory");
    *(bf16x8*)&Kt[krow * 136 + kc8]        = cvt8(ka00, ka01);
    *(bf16x8*)&Kt[(krow + 16) * 136 + kc8] = cvt8(ka10, ka11);
    {
      u16* v0 = &Vt[vc8 * 40 + vrow];
      v0[0*40] = f2b(va00.x); v0[1*40] = f2b(va00.y);
      v0[2*40] = f2b(va00.z); v0[3*40] = f2b(va00.w);
      v0[4*40] = f2b(va01.x); v0[5*40] = f2b(va01.y);
      v0[6*40] = f2b(va01.z); v0[7*40] = f2b(va01.w);
      u16* v1 = &Vt[(vc8 + 64) * 40 + vrow];
      v1[0*40] = f2b(va10.x); v1[1*40] = f2b(va10.y);
      v1[2*40] = f2b(va10.z); v1[3*40] = f2b(va10.w);
      v1[4*40] = f2b(va11.x); v1[5*40] = f2b(va11.y);
      v1[6*40] = f2b(va11.z); v1[7*40] = f2b(va11.w);
    }
    if (kt + 1 < NKT) {
      kp0 += KT * H_DIM; kp1 += KT * H_DIM; vp0 += KT * H_DIM; vp1 += KT * H_DIM;
      ka00 = *(const float4*)kp0; ka01 = *(const float4*)(kp0 + 4);
      ka10 = *(const float4*)kp1; ka11 = *(const float4*)(kp1 + 4);
      va00 = *(const float4*)vp0; va01 = *(const float4*)(vp0 + 4);
      va10 = *(const float4*)vp1; va11 = *(const float4*)(vp1 + 4);
    }
    asm volatile("s_waitcnt lgkmcnt(0)\n\ts_barrier" ::: "memory");

    f32x4 sc00 = {0,0,0,0}, sc01 = {0,0,0,0}, sc10 = {0,0,0,0}, sc11 = {0,0,0,0};
#pragma unroll
    for (int s = 0; s < 4; ++s) {
      bf16x8 kf0 = *(const bf16x8*)&Kt[col * 136 + s * 32 + quad * 8];
      bf16x8 kf1 = *(const bf16x8*)&Kt[(col + 16) * 136 + s * 32 + quad * 8];
      sc00 = __builtin_amdgcn_mfma_f32_16x16x32_bf16(qf[0][s], kf0, sc00, 0, 0, 0);
      sc01 = __builtin_amdgcn_mfma_f32_16x16x32_bf16(qf[0][s], kf1, sc01, 0, 0, 0);
      sc10 = __builtin_amdgcn_mfma_f32_16x16x32_bf16(qf[1][s], kf0, sc10, 0, 0, 0);
      sc11 = __builtin_amdgcn_mfma_f32_16x16x32_bf16(qf[1][s], kf1, sc11, 0, 0, 0);
    }

#pragma unroll
    for (int mi = 0; mi < 2; ++mi) {
      f32x4 s0 = mi ? sc10 : sc00;
      f32x4 s1 = mi ? sc11 : sc01;
#pragma unroll
      for (int i = 0; i < 4; ++i) {
        const int r = mi * 16 + quad * 4 + i;
        const int* mrow = Mb + (size_t)r * S_DIM + kt * KT;
        float p0 = mrow[col]      ? exp2f(s0[i]) : 0.f;
        float p1 = mrow[col + 16] ? exp2f(s1[i]) : 0.f;
        l_p[mi][i] += p0 + p1;
        Pw[r * P_STR + col]      = f2b(p0);
        Pw[r * P_STR + col + 16] = f2b(p1);
      }
    }

    bf16x8 pf0 = *(const bf16x8*)&Pw[col * P_STR + quad * 8];
    bf16x8 pf1 = *(const bf16x8*)&Pw[(col + 16) * P_STR + quad * 8];
#pragma unroll
    for (int c = 0; c < 8; ++c) {
      bf16x8 vf = *(const bf16x8*)&Vt[(c * 16 + col) * 40 + quad * 8];
      o[0][c] = __builtin_amdgcn_mfma_f32_16x16x32_bf16(pf0, vf, o[0][c], 0, 0, 0);
      o[1][c] = __builtin_amdgcn_mfma_f32_16x16x32_bf16(pf1, vf, o[1][c], 0, 0, 0);
    }
  }

  float* Oh = O + (size_t)head * T_DIM * H_DIM;
#pragma unroll
  for (int mi = 0; mi < 2; ++mi)
#pragma unroll
    for (int i = 0; i < 4; ++i) {
      float inv = 1.0f / red16_sum(l_p[mi][i]);
      float* orow = Oh + (size_t)(q0w + mi * 16 + quad * 4 + i) * H_DIM;
#pragma unroll
      for (int c = 0; c < 8; ++c)
        orow[c * 16 + col] = o[mi][c][i] * inv;
    }
}

extern "C" void kernel_launch(void* const* d_in, const int* in_sizes, int n_in,
                              void* d_out, int out_size, void* d_ws, size_t ws_size,
                              hipStream_t stream) {
  const float* q = (const float*)d_in[0];
  const float* k = (const float*)d_in[1];
  const float* v = (const float*)d_in[2];
  const int*   m = (const int*)d_in[3];
  float* out = (float*)d_out;

  if (d_ws != nullptr && ws_size >= WS_NEED) {
    u16* kb  = (u16*)((char*)d_ws + KB_OFF);
    u16* vtb = (u16*)((char*)d_ws + VT_OFF);
    u64* bm  = (u64*)((char*)d_ws + BM_OFF);
    prep_fused<<<dim3(PREP_BLOCKS), dim3(256), 0, stream>>>(k, kb, v, vtb, m, bm);
    attn_fwd<<<dim3(1024), dim3(256), 0, stream>>>(q, kb, vtb, (const u32*)bm, out);
  } else {
    attn_fb<<<dim3(1024), dim3(256), 0, stream>>>(q, k, v, m, out);
  }
}

// Round 9
// 437.963 us; speedup vs baseline: 1.2944x; 1.0003x over previous
//
#include <hip/hip_runtime.h>
#include <hip/hip_bf16.h>

typedef unsigned short u16;
typedef unsigned int u32;
typedef unsigned long long u64;
typedef short bf16x8 __attribute__((ext_vector_type(8)));
typedef float f32x4 __attribute__((ext_vector_type(4)));
typedef u32 u32x4 __attribute__((ext_vector_type(4)));

#define T_DIM 2048
#define S_DIM 2048
#define H_DIM 128
#define KT 32
#define NKT (S_DIM / KT)
#define P_STR 40
#define SCL 0.12753257480082588f  // (1/sqrt(128)) * log2(e): softmax in exp2 domain
#define NEG_BIG -1e30f

// workspace layout (bytes)
#define KB_OFF 0u
#define KB_BYTES (64u * 2048u * 128u * 2u)            // 32 MB bf16 K
#define VT_OFF KB_BYTES
#define VT_BYTES (64u * 2048u * 128u * 2u)            // 32 MB bf16 V^T tiled
#define BM_OFF (KB_BYTES + VT_BYTES)
#define BM_BYTES (2u * 2048u * 2048u / 8u)            // 1 MB bitmask
#define WS_NEED ((size_t)(BM_OFF + BM_BYTES))

static __device__ __forceinline__ u16 f2b(float x) {
  return __builtin_bit_cast(u16, __float2bfloat16(x));
}
static __device__ __forceinline__ bf16x8 cvt8(float4 a, float4 b) {
  bf16x8 f;
  f[0] = (short)f2b(a.x); f[1] = (short)f2b(a.y);
  f[2] = (short)f2b(a.z); f[3] = (short)f2b(a.w);
  f[4] = (short)f2b(b.x); f[5] = (short)f2b(b.y);
  f[6] = (short)f2b(b.z); f[7] = (short)f2b(b.w);
  return f;
}

// packed RNE f32x2 -> bf16x2 (no builtin on gfx950; single VOP3)
static __device__ __forceinline__ u32 cvtpk_bf16(float lo, float hi) {
  u32 r;
  asm("v_cvt_pk_bf16_f32 %0, %1, %2" : "=v"(r) : "v"(lo), "v"(hi));
  return r;
}
// v_permlane32_swap_b32: newA=[A.r0,A.r1,B.r0,B.r1], newB=[A.r2,A.r3,B.r2,B.r3] (r = 16-lane row)
static __device__ __forceinline__ void pl32_swap(u32& a, u32& b) {
  asm("v_permlane32_swap_b32 %0, %1" : "+v"(a), "+v"(b));
}
// v_permlane16_swap_b32: newA=[A.r0,B.r0,A.r2,B.r2], newB=[A.r1,B.r1,A.r3,B.r3]
static __device__ __forceinline__ void pl16_swap(u32& a, u32& b) {
  asm("v_permlane16_swap_b32 %0, %1" : "+v"(a), "+v"(b));
}

template<int CTRL>
static __device__ __forceinline__ float dppf(float x) {
  return __builtin_bit_cast(float,
    __builtin_amdgcn_update_dpp(0, __builtin_bit_cast(int, x), CTRL, 0xf, 0xf, true));
}
static __device__ __forceinline__ float red16_sum(float x) {
  x += dppf<0xB1>(x);
  x += dppf<0x4E>(x);
  x += dppf<0x141>(x);
  x += dppf<0x140>(x);
  return x;
}

// async global->LDS, 16 B per lane; LDS dest MUST be wave-uniform base
// (HW adds lane*16). Per-lane lds pointers are the round-4/7 bug.
static __device__ __forceinline__ void gl_lds16(const void* g, void* l) {
  __builtin_amdgcn_global_load_lds(
      (const __attribute__((address_space(1))) void*)g,
      (__attribute__((address_space(3))) void*)l, 16, 0, 0);
}

// ---------------- fused prep: cvt_k + vt_pack + pack_mask in one launch ----
// (verified round 6)
#define CVT_BLOCKS  8192
#define VTP_BLOCKS  4096
#define MSK_BLOCKS  ((2 * T_DIM) / 4)
#define PREP_BLOCKS (CVT_BLOCKS + VTP_BLOCKS + MSK_BLOCKS)

__global__ __launch_bounds__(256)
void prep_fused(const float* __restrict__ Ksrc, u16* __restrict__ Kdst,
                const float* __restrict__ V, u16* __restrict__ Vt,
                const int* __restrict__ M, u64* __restrict__ BM) {
  __shared__ u16 Lt[32][136];
  const int bid = blockIdx.x;
  const int tid = threadIdx.x;

  if (bid < CVT_BLOCKS) {
    // ---- cvt_k ----
    size_t g = (size_t)(bid * 256 + tid) * 8;
    float4 a = *(const float4*)(Ksrc + g);
    float4 b = *(const float4*)(Ksrc + g + 4);
    *(bf16x8*)(Kdst + g) = cvt8(a, b);
  } else if (bid < CVT_BLOCKS + VTP_BLOCKS) {
    // ---- vt_pack: V [head][s][h] fp32 -> Vt [head][s/32][h][32 keys] bf16 ----
    const int b2 = bid - CVT_BLOCKS;
    const int hd = b2 >> 6;
    const int t  = b2 & 63;
    const float* src = V + ((size_t)hd * S_DIM + (size_t)t * 32) * H_DIM;
    {
      int r = tid >> 3, h0 = (tid & 7) * 16;
      const float* sp = src + (size_t)r * H_DIM + h0;
      float4 a0 = *(const float4*)sp,      a1 = *(const float4*)(sp + 4);
      float4 a2 = *(const float4*)(sp + 8), a3 = *(const float4*)(sp + 12);
      *(bf16x8*)&Lt[r][h0]     = cvt8(a0, a1);
      *(bf16x8*)&Lt[r][h0 + 8] = cvt8(a2, a3);
    }
    __syncthreads();
    {
      int h = tid >> 1, k0 = (tid & 1) * 16;
      bf16x8 o0, o1;
#pragma unroll
      for (int j = 0; j < 8; ++j) o0[j] = (short)Lt[k0 + j][h];
#pragma unroll
      for (int j = 0; j < 8; ++j) o1[j] = (short)Lt[k0 + 8 + j][h];
      u16* dp = Vt + ((size_t)hd * 64 + t) * 4096 + (size_t)tid * 16;
      *(bf16x8*)dp = o0;
      *(bf16x8*)(dp + 8) = o1;
    }
  } else {
    // ---- pack_mask ----
    const int b3 = bid - (CVT_BLOCKS + VTP_BLOCKS);
    const int row  = b3 * 4 + (tid >> 6);
    const int lane = tid & 63;
    const int* mr = M + (size_t)row * S_DIM;
    u64* br = BM + (size_t)row * (S_DIM / 64);
    for (int s0 = 0; s0 < S_DIM; s0 += 64) {
      u64 b = __ballot(mr[s0 + lane] != 0);
      if (lane == 0) br[s0 >> 6] = b;
    }
  }
}

// ---------------- main fused kernel ----------------
// FINAL verified artifact (rounds 3 & 6, incl. graph-replay tripwires):
// swapped QK^T (mfma(K,Q) -> S^T, col=q), in-register P transpose via
// cvt_pk_bf16 + permlane{32,16}_swap (no P LDS round-trip), natural block
// order, KT=32, LDS pinned at 57344 B -> 2 blocks/CU (per-XCD resident set =
// 4 heads = 4 MB KV, exactly fits L2).
// FAILURE LEDGER (do not revisit):
//  - XCD swizzle + 4 blocks/CU: L2 thrash, 67->610 MB/iter, -26% (round 1)
//  - 64 q-rows/wave rewrite: wrong output (round 2)
//  - s_setprio / __builtin_amdgcn_exp2f on this structure: intermittent
//    wrongness, absmax ~2.1 (rounds 4/5)
//  - static LDS > 65536 B: silent launch failure (round 4)
//  - per-lane lds-DMA dest: wrong output (rounds 4/7)
//  - KT=64 (lbase fixed): first launch correct, ~5 us faster, but races
//    intermittently under graph replay (round 8) — retired.
__global__ __launch_bounds__(256, 2)
void attn_fwd(const float* __restrict__ Q, const u16* __restrict__ Kb,
              const u16* __restrict__ Vtb, const u32* __restrict__ BM,
              float* __restrict__ O)
{
  // double-buffered, XOR-chunk-swizzled tiles (no padding: lds-DMA layout)
  __shared__ __align__(16) u16 KT2[2][32 * 128];   // K tile: [key][h], chunk^=(key&15)
  __shared__ __align__(16) u16 VT2[2][128 * 32];   // Vt tile: [h][key], chunk^=(h&3)
  __shared__ __align__(16) float EPAD[6144];       // 24 KB: occupancy pin + epilogue scratch

  const int tid  = threadIdx.x;
  const int wave = tid >> 6;
  const int lane = tid & 63;
  const int col  = lane & 15;
  const int quad = lane >> 4;

  const int head   = blockIdx.x >> 4;
  const int qblock = blockIdx.x & 15;
  const int batch  = head >> 5;
  const int q0w    = qblock * 128 + wave * 32;

  const float* Qh   = Q + (size_t)head * T_DIM * H_DIM;
  const char*  kb_t = (const char*)(Kb  + (size_t)head * S_DIM * H_DIM);
  const char*  vt_t = (const char*)(Vtb + (size_t)head * S_DIM * H_DIM);
  // per-lane mask rows: q = q0w + col (mi=0) and q0w + 16 + col (mi=1)
  const u32*   bmr0 = BM + ((size_t)batch * T_DIM + q0w + col) * (S_DIM / 32);
  const u32*   bmr1 = bmr0 + (size_t)16 * (S_DIM / 32);

  // per-lane global byte offsets for the 2 K-issues and 2 V-issues (constant)
  int koffb[2], voffb[2], lbase[2];
#pragma unroll
  for (int i = 0; i < 2; ++i) {
    int slot = wave * 64 + lane + 256 * i;
    int kr = slot >> 4, kc = slot & 15;
    koffb[i] = kr * 256 + ((kc ^ (kr & 15)) << 4);
    int vh = slot >> 2, vc = slot & 3;
    voffb[i] = vh * 64 + (((vc ^ vh) & 3) << 4);
    lbase[i] = (wave * 64 + 256 * i) * 8;   // u16 index of wave's slot group (WAVE-UNIFORM)
  }

  // Q fragments, pre-scaled into exp2 domain. Used as MFMA *B* operand:
  // B[k=quad*8+j+32s][colq=lane&15], q-row = q0w + mi*16 + col.
  bf16x8 qf[2][4];
#pragma unroll
  for (int mi = 0; mi < 2; ++mi) {
    const float* qp = Qh + (size_t)(q0w + mi * 16 + col) * H_DIM + quad * 8;
#pragma unroll
    for (int s = 0; s < 4; ++s) {
      float4 a = *(const float4*)(qp + 32 * s);
      float4 b = *(const float4*)(qp + 32 * s + 4);
      a.x *= SCL; a.y *= SCL; a.z *= SCL; a.w *= SCL;
      b.x *= SCL; b.y *= SCL; b.z *= SCL; b.w *= SCL;
      qf[mi][s] = cvt8(a, b);
    }
  }

  f32x4 o[2][8];
#pragma unroll
  for (int mi = 0; mi < 2; ++mi)
#pragma unroll
    for (int c = 0; c < 8; ++c) o[mi][c] = (f32x4){0.f, 0.f, 0.f, 0.f};
  float l_p[2] = {0.f, 0.f};

  // stage tile 0
#pragma unroll
  for (int i = 0; i < 2; ++i) {
    gl_lds16(kb_t + koffb[i], (void*)&KT2[0][lbase[i]]);
    gl_lds16(vt_t + voffb[i], (void*)&VT2[0][lbase[i]]);
  }
  // mask words for tile 0 (pipelined one tile ahead)
  u32 wm0 = bmr0[0], wm1 = bmr1[0];

  for (int kt = 0; kt < NKT; ++kt) {
    // my tile-kt loads done; all waves past tile kt-1 compute
    asm volatile("s_waitcnt vmcnt(0) lgkmcnt(0)\n\ts_barrier" ::: "memory");

    if (kt + 1 < NKT) {
      const char* ks = kb_t + (size_t)(kt + 1) * 8192;
      const char* vs = vt_t + (size_t)(kt + 1) * 8192;
      const int nb = (kt + 1) & 1;
#pragma unroll
      for (int i = 0; i < 2; ++i) {
        gl_lds16(ks + koffb[i], (void*)&KT2[nb][lbase[i]]);
        gl_lds16(vs + voffb[i], (void*)&VT2[nb][lbase[i]]);
      }
    }

    const u16* Kc = &KT2[kt & 1][0];
    const u16* Vc = &VT2[kt & 1][0];

    u32 w0 = wm0, w1 = wm1;
    if (kt + 1 < NKT) { wm0 = bmr0[kt + 1]; wm1 = bmr1[kt + 1]; }

    // ---- swapped QK^T: S^T[key][q], D[row=key=4*quad+i (+16ki)][col=q] ----
    f32x4 s00 = {0,0,0,0}, s10 = {0,0,0,0}, s01 = {0,0,0,0}, s11 = {0,0,0,0};
#pragma unroll
    for (int s = 0; s < 4; ++s) {
      const int g = s * 4 + quad;
      bf16x8 kf0 = *(const bf16x8*)&Kc[col * 128 + ((g ^ col) & 15) * 8];
      bf16x8 kf1 = *(const bf16x8*)&Kc[(col + 16) * 128 + ((g ^ col) & 15) * 8];
      s00 = __builtin_amdgcn_mfma_f32_16x16x32_bf16(kf0, qf[0][s], s00, 0, 0, 0);
      s10 = __builtin_amdgcn_mfma_f32_16x16x32_bf16(kf1, qf[0][s], s10, 0, 0, 0);
      s01 = __builtin_amdgcn_mfma_f32_16x16x32_bf16(kf0, qf[1][s], s01, 0, 0, 0);
      s11 = __builtin_amdgcn_mfma_f32_16x16x32_bf16(kf1, qf[1][s], s11, 0, 0, 0);
    }

    // ---- softmax + in-register P transpose ----
    // lane holds P[key=16ki+4quad+i][q=16mi+col]; PV A-frag needs
    // P[q=16mi+col][key=8quad+j]: pack pairs, then quad redistribution via
    // permlane32_swap + permlane16_swap ({A,C}->{w0,w2}, {B,D}->{w1,w3}).
    bf16x8 pA[2];
#pragma unroll
    for (int mi = 0; mi < 2; ++mi) {
      f32x4 x0 = mi ? s01 : s00;   // keys 0..15 (local)
      f32x4 x1 = mi ? s11 : s10;   // keys 16..31
      u32 w = (mi ? w1 : w0) >> (quad * 4);
      float p0[4], p1[4];
#pragma unroll
      for (int i = 0; i < 4; ++i) {
        p0[i] = ((w >> i) & 1u)        ? exp2f(x0[i]) : 0.f;
        p1[i] = ((w >> (16 + i)) & 1u) ? exp2f(x1[i]) : 0.f;
      }
      l_p[mi] += ((p0[0] + p0[1]) + (p0[2] + p0[3])) +
                 ((p1[0] + p1[1]) + (p1[2] + p1[3]));
      u32 fa = cvtpk_bf16(p0[0], p0[1]);   // keys {4q, 4q+1}
      u32 fb = cvtpk_bf16(p0[2], p0[3]);   // keys {4q+2, 4q+3}
      u32 fc = cvtpk_bf16(p1[0], p1[1]);   // keys {16+4q, 17+4q}
      u32 fd = cvtpk_bf16(p1[2], p1[3]);   // keys {18+4q, 19+4q}
      pl32_swap(fa, fc); pl16_swap(fa, fc);  // fa=w0 {8q,8q+1}, fc=w2 {8q+4,8q+5}
      pl32_swap(fb, fd); pl16_swap(fb, fd);  // fb=w1 {8q+2,8q+3}, fd=w3 {8q+6,8q+7}
      u32x4 fr = {fa, fb, fc, fd};
      pA[mi] = __builtin_bit_cast(bf16x8, fr);
    }

    // ---- PV: O[32 x 128] += P[32 x 32] * V[32 x 128] ----
#pragma unroll
    for (int c = 0; c < 8; ++c) {
      bf16x8 vf = *(const bf16x8*)&Vc[(c * 16 + col) * 32 + ((quad ^ col) & 3) * 8];
      o[0][c] = __builtin_amdgcn_mfma_f32_16x16x32_bf16(pA[0], vf, o[0][c], 0, 0, 0);
      o[1][c] = __builtin_amdgcn_mfma_f32_16x16x32_bf16(pA[1], vf, o[1][c], 0, 0, 0);
    }
  }

  // ---- epilogue ----
  // l_p[mi] is the partial denominator for q = 16mi+col. Cross-quad reduce
  // in-register, redistribute q->(4quad+i) rows through 128 B/wave of EPAD.
  float* sred = &EPAD[wave * 32];
#pragma unroll
  for (int mi = 0; mi < 2; ++mi) {
    u32 a = __builtin_bit_cast(u32, l_p[mi]), b = a;
    pl32_swap(a, b);           // a=[x0,x1,x0,x1], b=[x2,x3,x2,x3] (by quad)
    float s2 = __builtin_bit_cast(float, a) + __builtin_bit_cast(float, b);
    u32 c = __builtin_bit_cast(u32, s2), d = c;
    pl16_swap(c, d);           // c=[s0,s0,s2,s2], d=[s1,s1,s3,s3]
    float tot = __builtin_bit_cast(float, c) + __builtin_bit_cast(float, d);
    if (quad == 0) sred[mi * 16 + col] = tot;
  }
  asm volatile("s_waitcnt lgkmcnt(0)" ::: "memory");

  float* Oh = O + (size_t)head * T_DIM * H_DIM;
#pragma unroll
  for (int mi = 0; mi < 2; ++mi) {
    float4 lv = *(const float4*)&sred[mi * 16 + quad * 4];
    float invs[4] = {1.0f / lv.x, 1.0f / lv.y, 1.0f / lv.z, 1.0f / lv.w};
#pragma unroll
    for (int i = 0; i < 4; ++i) {
      float* orow = Oh + (size_t)(q0w + mi * 16 + quad * 4 + i) * H_DIM;
#pragma unroll
      for (int c = 0; c < 8; ++c)
        orow[c * 16 + col] = o[mi][c][i] * invs[i];
    }
  }
}

// ---------------- fallback (R3-verified, fp32 direct, no workspace) ----------------
__global__ __launch_bounds__(256, 2)
void attn_fb(const float* __restrict__ Q, const float* __restrict__ K,
             const float* __restrict__ V, const int* __restrict__ M,
             float* __restrict__ O)
{
  __shared__ __align__(16) u16 Kt[32 * 136];
  __shared__ __align__(16) u16 Vt[H_DIM * 40];
  __shared__ __align__(16) u16 Pt[4][32 * P_STR];

  const int tid  = threadIdx.x;
  const int wave = tid >> 6;
  const int lane = tid & 63;
  const int col  = lane & 15;
  const int quad = lane >> 4;
  const int head   = blockIdx.x >> 4;
  const int qblock = blockIdx.x & 15;
  const int batch  = head >> 5;
  const int q0w    = qblock * 128 + wave * 32;

  const float* Qh = Q + (size_t)head * T_DIM * H_DIM;
  const float* Kp = K + (size_t)head * S_DIM * H_DIM;
  const float* Vp = V + (size_t)head * S_DIM * H_DIM;
  const int*   Mb = M + (size_t)batch * T_DIM * S_DIM + (size_t)q0w * S_DIM;

  const int krow = tid >> 4;
  const int kc8  = (tid & 15) * 8;
  const float* kp0 = Kp + (size_t)krow * H_DIM + kc8;
  const float* kp1 = kp0 + (size_t)16 * H_DIM;
  const int vrow = tid & 31;
  const int vc8  = (tid >> 5) * 8;
  const float* vp0 = Vp + (size_t)vrow * H_DIM + vc8;
  const float* vp1 = vp0 + 64;

  bf16x8 qf[2][4];
#pragma unroll
  for (int mi = 0; mi < 2; ++mi) {
    const float* qp = Qh + (size_t)(q0w + mi * 16 + col) * H_DIM + quad * 8;
#pragma unroll
    for (int s = 0; s < 4; ++s) {
      float4 a = *(const float4*)(qp + 32 * s);
      float4 b = *(const float4*)(qp + 32 * s + 4);
      a.x *= SCL; a.y *= SCL; a.z *= SCL; a.w *= SCL;
      b.x *= SCL; b.y *= SCL; b.z *= SCL; b.w *= SCL;
      qf[mi][s] = cvt8(a, b);
    }
  }

  f32x4 o[2][8];
#pragma unroll
  for (int mi = 0; mi < 2; ++mi)
#pragma unroll
    for (int c = 0; c < 8; ++c) o[mi][c] = (f32x4){0.f,0.f,0.f,0.f};
  float l_p[2][4] = {{0.f,0.f,0.f,0.f},{0.f,0.f,0.f,0.f}};

  float4 ka00 = *(const float4*)kp0, ka01 = *(const float4*)(kp0 + 4);
  float4 ka10 = *(const float4*)kp1, ka11 = *(const float4*)(kp1 + 4);
  float4 va00 = *(const float4*)vp0, va01 = *(const float4*)(vp0 + 4);
  float4 va10 = *(const float4*)vp1, va11 = *(const float4*)(vp1 + 4);

  u16* Pw = &Pt[wave][0];

  for (int kt = 0; kt < NKT; ++kt) {
    asm volatile("s_waitcnt lgkmcnt(0)\n\ts_barrier" ::: "memory");
    *(bf16x8*)&Kt[krow * 136 + kc8]        = cvt8(ka00, ka01);
    *(bf16x8*)&Kt[(krow + 16) * 136 + kc8] = cvt8(ka10, ka11);
    {
      u16* v0 = &Vt[vc8 * 40 + vrow];
      v0[0*40] = f2b(va00.x); v0[1*40] = f2b(va00.y);
      v0[2*40] = f2b(va00.z); v0[3*40] = f2b(va00.w);
      v0[4*40] = f2b(va01.x); v0[5*40] = f2b(va01.y);
      v0[6*40] = f2b(va01.z); v0[7*40] = f2b(va01.w);
      u16* v1 = &Vt[(vc8 + 64) * 40 + vrow];
      v1[0*40] = f2b(va10.x); v1[1*40] = f2b(va10.y);
      v1[2*40] = f2b(va10.z); v1[3*40] = f2b(va10.w);
      v1[4*40] = f2b(va11.x); v1[5*40] = f2b(va11.y);
      v1[6*40] = f2b(va11.z); v1[7*40] = f2b(va11.w);
    }
    if (kt + 1 < NKT) {
      kp0 += KT * H_DIM; kp1 += KT * H_DIM; vp0 += KT * H_DIM; vp1 += KT * H_DIM;
      ka00 = *(const float4*)kp0; ka01 = *(const float4*)(kp0 + 4);
      ka10 = *(const float4*)kp1; ka11 = *(const float4*)(kp1 + 4);
      va00 = *(const float4*)vp0; va01 = *(const float4*)(vp0 + 4);
      va10 = *(const float4*)vp1; va11 = *(const float4*)(vp1 + 4);
    }
    asm volatile("s_waitcnt lgkmcnt(0)\n\ts_barrier" ::: "memory");

    f32x4 sc00 = {0,0,0,0}, sc01 = {0,0,0,0}, sc10 = {0,0,0,0}, sc11 = {0,0,0,0};
#pragma unroll
    for (int s = 0; s < 4; ++s) {
      bf16x8 kf0 = *(const bf16x8*)&Kt[col * 136 + s * 32 + quad * 8];
      bf16x8 kf1 = *(const bf16x8*)&Kt[(col + 16) * 136 + s * 32 + quad * 8];
      sc00 = __builtin_amdgcn_mfma_f32_16x16x32_bf16(qf[0][s], kf0, sc00, 0, 0, 0);
      sc01 = __builtin_amdgcn_mfma_f32_16x16x32_bf16(qf[0][s], kf1, sc01, 0, 0, 0);
      sc10 = __builtin_amdgcn_mfma_f32_16x16x32_bf16(qf[1][s], kf0, sc10, 0, 0, 0);
      sc11 = __builtin_amdgcn_mfma_f32_16x16x32_bf16(qf[1][s], kf1, sc11, 0, 0, 0);
    }

#pragma unroll
    for (int mi = 0; mi < 2; ++mi) {
      f32x4 s0 = mi ? sc10 : sc00;
      f32x4 s1 = mi ? sc11 : sc01;
#pragma unroll
      for (int i = 0; i < 4; ++i) {
        const int r = mi * 16 + quad * 4 + i;
        const int* mrow = Mb + (size_t)r * S_DIM + kt * KT;
        float p0 = mrow[col]      ? exp2f(s0[i]) : 0.f;
        float p1 = mrow[col + 16] ? exp2f(s1[i]) : 0.f;
        l_p[mi][i] += p0 + p1;
        Pw[r * P_STR + col]      = f2b(p0);
        Pw[r * P_STR + col + 16] = f2b(p1);
      }
    }

    bf16x8 pf0 = *(const bf16x8*)&Pw[col * P_STR + quad * 8];
    bf16x8 pf1 = *(const bf16x8*)&Pw[(col + 16) * P_STR + quad * 8];
#pragma unroll
    for (int c = 0; c < 8; ++c) {
      bf16x8 vf = *(const bf16x8*)&Vt[(c * 16 + col) * 40 + quad * 8];
      o[0][c] = __builtin_amdgcn_mfma_f32_16x16x32_bf16(pf0, vf, o[0][c], 0, 0, 0);
      o[1][c] = __builtin_amdgcn_mfma_f32_16x16x32_bf16(pf1, vf, o[1][c], 0, 0, 0);
    }
  }

  float* Oh = O + (size_t)head * T_DIM * H_DIM;
#pragma unroll
  for (int mi = 0; mi < 2; ++mi)
#pragma unroll
    for (int i = 0; i < 4; ++i) {
      float inv = 1.0f / red16_sum(l_p[mi][i]);
      float* orow = Oh + (size_t)(q0w + mi * 16 + quad * 4 + i) * H_DIM;
#pragma unroll
      for (int c = 0; c < 8; ++c)
        orow[c * 16 + col] = o[mi][c][i] * inv;
    }
}

extern "C" void kernel_launch(void* const* d_in, const int* in_sizes, int n_in,
                              void* d_out, int out_size, void* d_ws, size_t ws_size,
                              hipStream_t stream) {
  const float* q = (const float*)d_in[0];
  const float* k = (const float*)d_in[1];
  const float* v = (const float*)d_in[2];
  const int*   m = (const int*)d_in[3];
  float* out = (float*)d_out;

  if (d_ws != nullptr && ws_size >= WS_NEED) {
    u16* kb  = (u16*)((char*)d_ws + KB_OFF);
    u16* vtb = (u16*)((char*)d_ws + VT_OFF);
    u64* bm  = (u64*)((char*)d_ws + BM_OFF);
    prep_fused<<<dim3(PREP_BLOCKS), dim3(256), 0, stream>>>(k, kb, v, vtb, m, bm);
    attn_fwd<<<dim3(1024), dim3(256), 0, stream>>>(q, kb, vtb, (const u32*)bm, out);
  } else {
    attn_fb<<<dim3(1024), dim3(256), 0, stream>>>(q, k, v, m, out);
  }
}

// Round 10
// 426.046 us; speedup vs baseline: 1.3306x; 1.0280x over previous
//
#include <hip/hip_runtime.h>
#include <hip/hip_bf16.h>

typedef unsigned short u16;
typedef unsigned int u32;
typedef unsigned long long u64;
typedef short bf16x8 __attribute__((ext_vector_type(8)));
typedef float f32x4 __attribute__((ext_vector_type(4)));
typedef u32 u32x4 __attribute__((ext_vector_type(4)));

#define T_DIM 2048
#define S_DIM 2048
#define H_DIM 128
#define KT 32
#define NKT (S_DIM / KT)
#define P_STR 40
#define SCL 0.12753257480082588f  // (1/sqrt(128)) * log2(e): softmax in exp2 domain
#define NEG_BIG -1e30f

// workspace layout (bytes)
#define KB_OFF 0u
#define KB_BYTES (64u * 2048u * 128u * 2u)            // 32 MB bf16 K
#define VT_OFF KB_BYTES
#define VT_BYTES (64u * 2048u * 128u * 2u)            // 32 MB bf16 V^T tiled
#define BM_OFF (KB_BYTES + VT_BYTES)
#define BM_BYTES (2u * 2048u * 2048u / 8u)            // 1 MB bitmask
#define WS_NEED ((size_t)(BM_OFF + BM_BYTES))

static __device__ __forceinline__ u16 f2b(float x) {
  return __builtin_bit_cast(u16, __float2bfloat16(x));
}
static __device__ __forceinline__ bf16x8 cvt8(float4 a, float4 b) {
  bf16x8 f;
  f[0] = (short)f2b(a.x); f[1] = (short)f2b(a.y);
  f[2] = (short)f2b(a.z); f[3] = (short)f2b(a.w);
  f[4] = (short)f2b(b.x); f[5] = (short)f2b(b.y);
  f[6] = (short)f2b(b.z); f[7] = (short)f2b(b.w);
  return f;
}

// packed RNE f32x2 -> bf16x2 (no builtin on gfx950; single VOP3)
static __device__ __forceinline__ u32 cvtpk_bf16(float lo, float hi) {
  u32 r;
  asm("v_cvt_pk_bf16_f32 %0, %1, %2" : "=v"(r) : "v"(lo), "v"(hi));
  return r;
}
// v_permlane32_swap_b32: newA=[A.r0,A.r1,B.r0,B.r1], newB=[A.r2,A.r3,B.r2,B.r3] (r = 16-lane row)
static __device__ __forceinline__ void pl32_swap(u32& a, u32& b) {
  asm("v_permlane32_swap_b32 %0, %1" : "+v"(a), "+v"(b));
}
// v_permlane16_swap_b32: newA=[A.r0,B.r0,A.r2,B.r2], newB=[A.r1,B.r1,A.r3,B.r3]
static __device__ __forceinline__ void pl16_swap(u32& a, u32& b) {
  asm("v_permlane16_swap_b32 %0, %1" : "+v"(a), "+v"(b));
}

template<int CTRL>
static __device__ __forceinline__ float dppf(float x) {
  return __builtin_bit_cast(float,
    __builtin_amdgcn_update_dpp(0, __builtin_bit_cast(int, x), CTRL, 0xf, 0xf, true));
}
static __device__ __forceinline__ float red16_sum(float x) {
  x += dppf<0xB1>(x);
  x += dppf<0x4E>(x);
  x += dppf<0x141>(x);
  x += dppf<0x140>(x);
  return x;
}

// async global->LDS, 16 B per lane; LDS dest MUST be wave-uniform base
// (HW adds lane*16). Per-lane lds pointers are the round-4/7 bug.
static __device__ __forceinline__ void gl_lds16(const void* g, void* l) {
  __builtin_amdgcn_global_load_lds(
      (const __attribute__((address_space(1))) void*)g,
      (__attribute__((address_space(3))) void*)l, 16, 0, 0);
}

// ---------------- fused prep: cvt_k + vt_pack + pack_mask in one launch ----
// (verified round 6)
#define CVT_BLOCKS  8192
#define VTP_BLOCKS  4096
#define MSK_BLOCKS  ((2 * T_DIM) / 4)
#define PREP_BLOCKS (CVT_BLOCKS + VTP_BLOCKS + MSK_BLOCKS)

__global__ __launch_bounds__(256)
void prep_fused(const float* __restrict__ Ksrc, u16* __restrict__ Kdst,
                const float* __restrict__ V, u16* __restrict__ Vt,
                const int* __restrict__ M, u64* __restrict__ BM) {
  __shared__ u16 Lt[32][136];
  const int bid = blockIdx.x;
  const int tid = threadIdx.x;

  if (bid < CVT_BLOCKS) {
    // ---- cvt_k ----
    size_t g = (size_t)(bid * 256 + tid) * 8;
    float4 a = *(const float4*)(Ksrc + g);
    float4 b = *(const float4*)(Ksrc + g + 4);
    *(bf16x8*)(Kdst + g) = cvt8(a, b);
  } else if (bid < CVT_BLOCKS + VTP_BLOCKS) {
    // ---- vt_pack: V [head][s][h] fp32 -> Vt [head][s/32][h][32 keys] bf16 ----
    const int b2 = bid - CVT_BLOCKS;
    const int hd = b2 >> 6;
    const int t  = b2 & 63;
    const float* src = V + ((size_t)hd * S_DIM + (size_t)t * 32) * H_DIM;
    {
      int r = tid >> 3, h0 = (tid & 7) * 16;
      const float* sp = src + (size_t)r * H_DIM + h0;
      float4 a0 = *(const float4*)sp,      a1 = *(const float4*)(sp + 4);
      float4 a2 = *(const float4*)(sp + 8), a3 = *(const float4*)(sp + 12);
      *(bf16x8*)&Lt[r][h0]     = cvt8(a0, a1);
      *(bf16x8*)&Lt[r][h0 + 8] = cvt8(a2, a3);
    }
    __syncthreads();
    {
      int h = tid >> 1, k0 = (tid & 1) * 16;
      bf16x8 o0, o1;
#pragma unroll
      for (int j = 0; j < 8; ++j) o0[j] = (short)Lt[k0 + j][h];
#pragma unroll
      for (int j = 0; j < 8; ++j) o1[j] = (short)Lt[k0 + 8 + j][h];
      u16* dp = Vt + ((size_t)hd * 64 + t) * 4096 + (size_t)tid * 16;
      *(bf16x8*)dp = o0;
      *(bf16x8*)(dp + 8) = o1;
    }
  } else {
    // ---- pack_mask ----
    const int b3 = bid - (CVT_BLOCKS + VTP_BLOCKS);
    const int row  = b3 * 4 + (tid >> 6);
    const int lane = tid & 63;
    const int* mr = M + (size_t)row * S_DIM;
    u64* br = BM + (size_t)row * (S_DIM / 64);
    for (int s0 = 0; s0 < S_DIM; s0 += 64) {
      u64 b = __ballot(mr[s0 + lane] != 0);
      if (lane == 0) br[s0 >> 6] = b;
    }
  }
}

// ---------------- main fused kernel ----------------
// Verified round-3/6/9 structure (swapped QK^T, in-register P transpose,
// natural block order, KT=32, 2 blocks/CU) with ONE functional delta:
// the softmax denominator moves off the VALU onto the MFMA pipe via a
// ones-column MFMA — o_l[mi] = mfma(pA[mi], ones, o_l[mi]) gives each lane
// l for exactly the q-rows it writes (D layout: row = quad*4+i). Removes
// 16 VALU adds/tile and the cross-quad epilogue reduce. No sync changes.
// FAILURE LEDGER (do not revisit):
//  - XCD swizzle + 4 blocks/CU: L2 thrash, -26% (round 1)
//  - 64 q-rows/wave rewrite: wrong output (round 2)
//  - s_setprio / __builtin_amdgcn_exp2f: intermittent wrongness (rounds 4/5)
//  - static LDS > 65536 B: silent launch failure (round 4)
//  - per-lane lds-DMA dest: wrong output (rounds 4/7)
//  - KT=64: races intermittently under graph replay (round 8) — retired.
__global__ __launch_bounds__(256, 2)
void attn_fwd(const float* __restrict__ Q, const u16* __restrict__ Kb,
              const u16* __restrict__ Vtb, const u32* __restrict__ BM,
              float* __restrict__ O)
{
  // double-buffered, XOR-chunk-swizzled tiles (no padding: lds-DMA layout)
  __shared__ __align__(16) u16 KT2[2][32 * 128];   // K tile: [key][h], chunk^=(key&15)
  __shared__ __align__(16) u16 VT2[2][128 * 32];   // Vt tile: [h][key], chunk^=(h&3)
  __shared__ __align__(16) float EPAD[6144];       // 24 KB occupancy pin (2 blocks/CU)

  const int tid  = threadIdx.x;
  const int wave = tid >> 6;
  const int lane = tid & 63;
  const int col  = lane & 15;
  const int quad = lane >> 4;

  const int head   = blockIdx.x >> 4;
  const int qblock = blockIdx.x & 15;
  const int batch  = head >> 5;
  const int q0w    = qblock * 128 + wave * 32;

  const float* Qh   = Q + (size_t)head * T_DIM * H_DIM;
  const char*  kb_t = (const char*)(Kb  + (size_t)head * S_DIM * H_DIM);
  const char*  vt_t = (const char*)(Vtb + (size_t)head * S_DIM * H_DIM);
  // per-lane mask rows: q = q0w + col (mi=0) and q0w + 16 + col (mi=1)
  const u32*   bmr0 = BM + ((size_t)batch * T_DIM + q0w + col) * (S_DIM / 32);
  const u32*   bmr1 = bmr0 + (size_t)16 * (S_DIM / 32);

  // per-lane global byte offsets for the 2 K-issues and 2 V-issues (constant)
  int koffb[2], voffb[2], lbase[2];
#pragma unroll
  for (int i = 0; i < 2; ++i) {
    int slot = wave * 64 + lane + 256 * i;
    int kr = slot >> 4, kc = slot & 15;
    koffb[i] = kr * 256 + ((kc ^ (kr & 15)) << 4);
    int vh = slot >> 2, vc = slot & 3;
    voffb[i] = vh * 64 + (((vc ^ vh) & 3) << 4);
    lbase[i] = (wave * 64 + 256 * i) * 8;   // u16 index of wave's slot group (WAVE-UNIFORM)
  }

  // Q fragments, pre-scaled into exp2 domain. Used as MFMA *B* operand:
  // B[k=quad*8+j+32s][colq=lane&15], q-row = q0w + mi*16 + col.
  bf16x8 qf[2][4];
#pragma unroll
  for (int mi = 0; mi < 2; ++mi) {
    const float* qp = Qh + (size_t)(q0w + mi * 16 + col) * H_DIM + quad * 8;
#pragma unroll
    for (int s = 0; s < 4; ++s) {
      float4 a = *(const float4*)(qp + 32 * s);
      float4 b = *(const float4*)(qp + 32 * s + 4);
      a.x *= SCL; a.y *= SCL; a.z *= SCL; a.w *= SCL;
      b.x *= SCL; b.y *= SCL; b.z *= SCL; b.w *= SCL;
      qf[mi][s] = cvt8(a, b);
    }
  }

  // all-ones bf16 B-operand for the denominator MFMA
  bf16x8 ones;
#pragma unroll
  for (int j = 0; j < 8; ++j) ones[j] = (short)0x3F80;

  f32x4 o[2][8];
#pragma unroll
  for (int mi = 0; mi < 2; ++mi)
#pragma unroll
    for (int c = 0; c < 8; ++c) o[mi][c] = (f32x4){0.f, 0.f, 0.f, 0.f};
  f32x4 o_l[2] = {(f32x4){0.f,0.f,0.f,0.f}, (f32x4){0.f,0.f,0.f,0.f}};

  // stage tile 0
#pragma unroll
  for (int i = 0; i < 2; ++i) {
    gl_lds16(kb_t + koffb[i], (void*)&KT2[0][lbase[i]]);
    gl_lds16(vt_t + voffb[i], (void*)&VT2[0][lbase[i]]);
  }
  // mask words for tile 0 (pipelined one tile ahead)
  u32 wm0 = bmr0[0], wm1 = bmr1[0];

  for (int kt = 0; kt < NKT; ++kt) {
    // my tile-kt loads done; all waves past tile kt-1 compute
    asm volatile("s_waitcnt vmcnt(0) lgkmcnt(0)\n\ts_barrier" ::: "memory");

    if (kt + 1 < NKT) {
      const char* ks = kb_t + (size_t)(kt + 1) * 8192;
      const char* vs = vt_t + (size_t)(kt + 1) * 8192;
      const int nb = (kt + 1) & 1;
#pragma unroll
      for (int i = 0; i < 2; ++i) {
        gl_lds16(ks + koffb[i], (void*)&KT2[nb][lbase[i]]);
        gl_lds16(vs + voffb[i], (void*)&VT2[nb][lbase[i]]);
      }
    }

    const u16* Kc = &KT2[kt & 1][0];
    const u16* Vc = &VT2[kt & 1][0];

    u32 w0 = wm0, w1 = wm1;
    if (kt + 1 < NKT) { wm0 = bmr0[kt + 1]; wm1 = bmr1[kt + 1]; }

    // ---- swapped QK^T: S^T[key][q], D[row=key=4*quad+i (+16ki)][col=q] ----
    f32x4 s00 = {0,0,0,0}, s10 = {0,0,0,0}, s01 = {0,0,0,0}, s11 = {0,0,0,0};
#pragma unroll
    for (int s = 0; s < 4; ++s) {
      const int g = s * 4 + quad;
      bf16x8 kf0 = *(const bf16x8*)&Kc[col * 128 + ((g ^ col) & 15) * 8];
      bf16x8 kf1 = *(const bf16x8*)&Kc[(col + 16) * 128 + ((g ^ col) & 15) * 8];
      s00 = __builtin_amdgcn_mfma_f32_16x16x32_bf16(kf0, qf[0][s], s00, 0, 0, 0);
      s10 = __builtin_amdgcn_mfma_f32_16x16x32_bf16(kf1, qf[0][s], s10, 0, 0, 0);
      s01 = __builtin_amdgcn_mfma_f32_16x16x32_bf16(kf0, qf[1][s], s01, 0, 0, 0);
      s11 = __builtin_amdgcn_mfma_f32_16x16x32_bf16(kf1, qf[1][s], s11, 0, 0, 0);
    }

    // ---- softmax + in-register P transpose ----
    // lane holds P[key=16ki+4quad+i][q=16mi+col]; PV A-frag needs
    // P[q=16mi+col][key=8quad+j]: pack pairs, then quad redistribution via
    // permlane32_swap + permlane16_swap ({A,C}->{w0,w2}, {B,D}->{w1,w3}).
    bf16x8 pA[2];
#pragma unroll
    for (int mi = 0; mi < 2; ++mi) {
      f32x4 x0 = mi ? s01 : s00;   // keys 0..15 (local)
      f32x4 x1 = mi ? s11 : s10;   // keys 16..31
      u32 w = (mi ? w1 : w0) >> (quad * 4);
      float p0[4], p1[4];
#pragma unroll
      for (int i = 0; i < 4; ++i) {
        p0[i] = ((w >> i) & 1u)        ? exp2f(x0[i]) : 0.f;
        p1[i] = ((w >> (16 + i)) & 1u) ? exp2f(x1[i]) : 0.f;
      }
      u32 fa = cvtpk_bf16(p0[0], p0[1]);   // keys {4q, 4q+1}
      u32 fb = cvtpk_bf16(p0[2], p0[3]);   // keys {4q+2, 4q+3}
      u32 fc = cvtpk_bf16(p1[0], p1[1]);   // keys {16+4q, 17+4q}
      u32 fd = cvtpk_bf16(p1[2], p1[3]);   // keys {18+4q, 19+4q}
      pl32_swap(fa, fc); pl16_swap(fa, fc);  // fa=w0 {8q,8q+1}, fc=w2 {8q+4,8q+5}
      pl32_swap(fb, fd); pl16_swap(fb, fd);  // fb=w1 {8q+2,8q+3}, fd=w3 {8q+6,8q+7}
      u32x4 fr = {fa, fb, fc, fd};
      pA[mi] = __builtin_bit_cast(bf16x8, fr);
    }

    // ---- PV: O[32 x 128] += P[32 x 32] * V[32 x 128], plus the
    //      denominator column: o_l[mi][i] += sum_k P[q-row][k] ----
    o_l[0] = __builtin_amdgcn_mfma_f32_16x16x32_bf16(pA[0], ones, o_l[0], 0, 0, 0);
    o_l[1] = __builtin_amdgcn_mfma_f32_16x16x32_bf16(pA[1], ones, o_l[1], 0, 0, 0);
#pragma unroll
    for (int c = 0; c < 8; ++c) {
      bf16x8 vf = *(const bf16x8*)&Vc[(c * 16 + col) * 32 + ((quad ^ col) & 3) * 8];
      o[0][c] = __builtin_amdgcn_mfma_f32_16x16x32_bf16(pA[0], vf, o[0][c], 0, 0, 0);
      o[1][c] = __builtin_amdgcn_mfma_f32_16x16x32_bf16(pA[1], vf, o[1][c], 0, 0, 0);
    }
  }

  // ---- epilogue ----
  // o_l[mi][i] = l for q-row q0w + mi*16 + quad*4 + i (D layout: same rows
  // this lane writes) — lane-local, no reduce, no scratch needed.
  // Keep the 24 KB EPAD allocated anyway (occupancy pin, round-1 lesson):
  // genuine store + load feeding an asm sink so it cannot be DCE'd.
  EPAD[tid] = o_l[0][0] + o_l[1][3];
  asm volatile("s_waitcnt lgkmcnt(0)" ::: "memory");
  {
    float ka = EPAD[tid];
    asm volatile("" : : "v"(ka) : "memory");
  }

  float* Oh = O + (size_t)head * T_DIM * H_DIM;
#pragma unroll
  for (int mi = 0; mi < 2; ++mi) {
#pragma unroll
    for (int i = 0; i < 4; ++i) {
      float inv = 1.0f / o_l[mi][i];
      float* orow = Oh + (size_t)(q0w + mi * 16 + quad * 4 + i) * H_DIM;
#pragma unroll
      for (int c = 0; c < 8; ++c)
        orow[c * 16 + col] = o[mi][c][i] * inv;
    }
  }
}

// ---------------- fallback (R3-verified, fp32 direct, no workspace) ----------------
__global__ __launch_bounds__(256, 2)
void attn_fb(const float* __restrict__ Q, const float* __restrict__ K,
             const float* __restrict__ V, const int* __restrict__ M,
             float* __restrict__ O)
{
  __shared__ __align__(16) u16 Kt[32 * 136];
  __shared__ __align__(16) u16 Vt[H_DIM * 40];
  __shared__ __align__(16) u16 Pt[4][32 * P_STR];

  const int tid  = threadIdx.x;
  const int wave = tid >> 6;
  const int lane = tid & 63;
  const int col  = lane & 15;
  const int quad = lane >> 4;
  const int head   = blockIdx.x >> 4;
  const int qblock = blockIdx.x & 15;
  const int batch  = head >> 5;
  const int q0w    = qblock * 128 + wave * 32;

  const float* Qh = Q + (size_t)head * T_DIM * H_DIM;
  const float* Kp = K + (size_t)head * S_DIM * H_DIM;
  const float* Vp = V + (size_t)head * S_DIM * H_DIM;
  const int*   Mb = M + (size_t)batch * T_DIM * S_DIM + (size_t)q0w * S_DIM;

  const int krow = tid >> 4;
  const int kc8  = (tid & 15) * 8;
  const float* kp0 = Kp + (size_t)krow * H_DIM + kc8;
  const float* kp1 = kp0 + (size_t)16 * H_DIM;
  const int vrow = tid & 31;
  const int vc8  = (tid >> 5) * 8;
  const float* vp0 = Vp + (size_t)vrow * H_DIM + vc8;
  const float* vp1 = vp0 + 64;

  bf16x8 qf[2][4];
#pragma unroll
  for (int mi = 0; mi < 2; ++mi) {
    const float* qp = Qh + (size_t)(q0w + mi * 16 + col) * H_DIM + quad * 8;
#pragma unroll
    for (int s = 0; s < 4; ++s) {
      float4 a = *(const float4*)(qp + 32 * s);
      float4 b = *(const float4*)(qp + 32 * s + 4);
      a.x *= SCL; a.y *= SCL; a.z *= SCL; a.w *= SCL;
      b.x *= SCL; b.y *= SCL; b.z *= SCL; b.w *= SCL;
      qf[mi][s] = cvt8(a, b);
    }
  }

  f32x4 o[2][8];
#pragma unroll
  for (int mi = 0; mi < 2; ++mi)
#pragma unroll
    for (int c = 0; c < 8; ++c) o[mi][c] = (f32x4){0.f,0.f,0.f,0.f};
  float l_p[2][4] = {{0.f,0.f,0.f,0.f},{0.f,0.f,0.f,0.f}};

  float4 ka00 = *(const float4*)kp0, ka01 = *(const float4*)(kp0 + 4);
  float4 ka10 = *(const float4*)kp1, ka11 = *(const float4*)(kp1 + 4);
  float4 va00 = *(const float4*)vp0, va01 = *(const float4*)(vp0 + 4);
  float4 va10 = *(const float4*)vp1, va11 = *(const float4*)(vp1 + 4);

  u16* Pw = &Pt[wave][0];

  for (int kt = 0; kt < NKT; ++kt) {
    asm volatile("s_waitcnt lgkmcnt(0)\n\ts_barrier" ::: "memory");
    *(bf16x8*)&Kt[krow * 136 + kc8]        = cvt8(ka00, ka01);
    *(bf16x8*)&Kt[(krow + 16) * 136 + kc8] = cvt8(ka10, ka11);
    {
      u16* v0 = &Vt[vc8 * 40 + vrow];
      v0[0*40] = f2b(va00.x); v0[1*40] = f2b(va00.y);
      v0[2*40] = f2b(va00.z); v0[3*40] = f2b(va00.w);
      v0[4*40] = f2b(va01.x); v0[5*40] = f2b(va01.y);
      v0[6*40] = f2b(va01.z); v0[7*40] = f2b(va01.w);
      u16* v1 = &Vt[(vc8 + 64) * 40 + vrow];
      v1[0*40] = f2b(va10.x); v1[1*40] = f2b(va10.y);
      v1[2*40] = f2b(va10.z); v1[3*40] = f2b(va10.w);
      v1[4*40] = f2b(va11.x); v1[5*40] = f2b(va11.y);
      v1[6*40] = f2b(va11.z); v1[7*40] = f2b(va11.w);
    }
    if (kt + 1 < NKT) {
      kp0 += KT * H_DIM; kp1 += KT * H_DIM; vp0 += KT * H_DIM; vp1 += KT * H_DIM;
      ka00 = *(const float4*)kp0; ka01 = *(const float4*)(kp0 + 4);
      ka10 = *(const float4*)kp1; ka11 = *(const float4*)(kp1 + 4);
      va00 = *(const float4*)vp0; va01 = *(const float4*)(vp0 + 4);
      va10 = *(const float4*)vp1; va11 = *(const float4*)(vp1 + 4);
    }
    asm volatile("s_waitcnt lgkmcnt(0)\n\ts_barrier" ::: "memory");

    f32x4 sc00 = {0,0,0,0}, sc01 = {0,0,0,0}, sc10 = {0,0,0,0}, sc11 = {0,0,0,0};
#pragma unroll
    for (int s = 0; s < 4; ++s) {
      bf16x8 kf0 = *(const bf16x8*)&Kt[col * 136 + s * 32 + quad * 8];
      bf16x8 kf1 = *(const bf16x8*)&Kt[(col + 16) * 136 + s * 32 + quad * 8];
      sc00 = __builtin_amdgcn_mfma_f32_16x16x32_bf16(qf[0][s], kf0, sc00, 0, 0, 0);
      sc01 = __builtin_amdgcn_mfma_f32_16x16x32_bf16(qf[0][s], kf1, sc01, 0, 0, 0);
      sc10 = __builtin_amdgcn_mfma_f32_16x16x32_bf16(qf[1][s], kf0, sc10, 0, 0, 0);
      sc11 = __builtin_amdgcn_mfma_f32_16x16x32_bf16(qf[1][s], kf1, sc11, 0, 0, 0);
    }

#pragma unroll
    for (int mi = 0; mi < 2; ++mi) {
      f32x4 s0 = mi ? sc10 : sc00;
      f32x4 s1 = mi ? sc11 : sc01;
#pragma unroll
      for (int i = 0; i < 4; ++i) {
        const int r = mi * 16 + quad * 4 + i;
        const int* mrow = Mb + (size_t)r * S_DIM + kt * KT;
        float p0 = mrow[col]      ? exp2f(s0[i]) : 0.f;
        float p1 = mrow[col + 16] ? exp2f(s1[i]) : 0.f;
        l_p[mi][i] += p0 + p1;
        Pw[r * P_STR + col]      = f2b(p0);
        Pw[r * P_STR + col + 16] = f2b(p1);
      }
    }

    bf16x8 pf0 = *(const bf16x8*)&Pw[col * P_STR + quad * 8];
    bf16x8 pf1 = *(const bf16x8*)&Pw[(col + 16) * P_STR + quad * 8];
#pragma unroll
    for (int c = 0; c < 8; ++c) {
      bf16x8 vf = *(const bf16x8*)&Vt[(c * 16 + col) * 40 + quad * 8];
      o[0][c] = __builtin_amdgcn_mfma_f32_16x16x32_bf16(pf0, vf, o[0][c], 0, 0, 0);
      o[1][c] = __builtin_amdgcn_mfma_f32_16x16x32_bf16(pf1, vf, o[1][c], 0, 0, 0);
    }
  }

  float* Oh = O + (size_t)head * T_DIM * H_DIM;
#pragma unroll
  for (int mi = 0; mi < 2; ++mi)
#pragma unroll
    for (int i = 0; i < 4; ++i) {
      float inv = 1.0f / red16_sum(l_p[mi][i]);
      float* orow = Oh + (size_t)(q0w + mi * 16 + quad * 4 + i) * H_DIM;
#pragma unroll
      for (int c = 0; c < 8; ++c)
        orow[c * 16 + col] = o[mi][c][i] * inv;
    }
}

extern "C" void kernel_launch(void* const* d_in, const int* in_sizes, int n_in,
                              void* d_out, int out_size, void* d_ws, size_t ws_size,
                              hipStream_t stream) {
  const float* q = (const float*)d_in[0];
  const float* k = (const float*)d_in[1];
  const float* v = (const float*)d_in[2];
  const int*   m = (const int*)d_in[3];
  float* out = (float*)d_out;

  if (d_ws != nullptr && ws_size >= WS_NEED) {
    u16* kb  = (u16*)((char*)d_ws + KB_OFF);
    u16* vtb = (u16*)((char*)d_ws + VT_OFF);
    u64* bm  = (u64*)((char*)d_ws + BM_OFF);
    prep_fused<<<dim3(PREP_BLOCKS), dim3(256), 0, stream>>>(k, kb, v, vtb, m, bm);
    attn_fwd<<<dim3(1024), dim3(256), 0, stream>>>(q, kb, vtb, (const u32*)bm, out);
  } else {
    attn_fb<<<dim3(1024), dim3(256), 0, stream>>>(q, k, v, m, out);
  }
}